// Round 7
// baseline (1359.168 us; speedup 1.0000x reference)
//
#include <hip/hip_runtime.h>

#define NMAP 128
#define EPSV 1e-5f
#define SCHUNK 2048     // elements per scan block (256 thr x 8)
#define HSTR 136        // LDS h-tile row stride in shorts (272 B)
#define BKSH 8          // 256 nodes per bucket
#define CH 8192         // edges per bucket_scatter workgroup

typedef __attribute__((ext_vector_type(8))) short bf16x8;   // 8 bf16 = 4 VGPRs
typedef __attribute__((ext_vector_type(4))) float f32x4;

__device__ __forceinline__ unsigned short f2bf(float f) {
    union { float f; unsigned u; } x; x.f = f;
    unsigned u = x.u;
    return (unsigned short)((u + 0x7fffu + ((u >> 16) & 1u)) >> 16);  // RNE
}
__device__ __forceinline__ float bf2f(unsigned short h) {
    union { unsigned u; float f; } x; x.u = ((unsigned)h) << 16;
    return x.f;
}

struct __align__(16) FSmem {
    unsigned short h[64 * HSTR];    // 17408 B  bf16 h-tile [64][136]
    float red[2][16][65];           //  8320 B  GN partial sums
    float mv[64][2];                //   512 B  mean/rstd per row
};

// per-row mean/rstd over 128 cols of acc -> s.mv  (two internal barriers)
__device__ __forceinline__ void gn_stats(FSmem& s, const f32x4 acc[4][2],
                                         int w, int l15, int lhi, int tid)
{
    const int cg = w * 4 + (l15 >> 2);
    #pragma unroll
    for (int mi = 0; mi < 4; ++mi) {
        #pragma unroll
        for (int j = 0; j < 4; ++j) {
            float a0 = acc[mi][0][j], a1 = acc[mi][1][j];
            float s0 = a0 + a1, s1 = a0 * a0 + a1 * a1;
            s0 += __shfl_xor(s0, 1); s0 += __shfl_xor(s0, 2);
            s1 += __shfl_xor(s1, 1); s1 += __shfl_xor(s1, 2);
            if ((l15 & 3) == 0) {
                int row = mi * 16 + lhi * 4 + j;
                s.red[0][cg][row] = s0;
                s.red[1][cg][row] = s1;
            }
        }
    }
    __syncthreads();
    if (tid < 64) {
        float sm = 0.f, ss = 0.f;
        #pragma unroll
        for (int c2 = 0; c2 < 16; ++c2) { sm += s.red[0][c2][tid]; ss += s.red[1][c2][tid]; }
        float mean = sm * (1.f / 128.f);
        float var = ss * (1.f / 128.f) - mean * mean;
        s.mv[tid][0] = mean;
        s.mv[tid][1] = rsqrtf(var + EPSV);
    }
    __syncthreads();
}

// acc += h_lds @ WT[kwoff..]   (A from s.h cols [0,nks*32), weight K-offset kwoff)
__device__ __forceinline__ void gemm_lds(f32x4 acc[4][2], const FSmem& s,
    const unsigned short* __restrict__ WT, int K, int kwoff, int nks,
    int w, int l15, int lhi)
{
    #pragma unroll
    for (int ks = 0; ks < nks; ++ks) {
        bf16x8 af[4], bfr[2];
        #pragma unroll
        for (int mi = 0; mi < 4; ++mi)
            af[mi] = *(const bf16x8*)&s.h[(mi * 16 + l15) * HSTR + ks * 32 + lhi * 8];
        #pragma unroll
        for (int ni = 0; ni < 2; ++ni)
            bfr[ni] = *(const bf16x8*)&WT[(size_t)(w * 32 + ni * 16 + l15) * K + kwoff + ks * 32 + lhi * 8];
        #pragma unroll
        for (int mi = 0; mi < 4; ++mi)
            #pragma unroll
            for (int ni = 0; ni < 2; ++ni)
                acc[mi][ni] = __builtin_amdgcn_mfma_f32_16x16x32_bf16(
                    af[mi], bfr[ni], acc[mi][ni], 0, 0, 0);
    }
}

// acc += X[rowtile] @ WT[k0w..k0w+nks*32)   (A from global, ldx row stride)
__device__ __forceinline__ void gemm_glb(f32x4 acc[4][2],
    const unsigned short* __restrict__ X, int ldx, int k0w,
    const unsigned short* __restrict__ WT, int K, int nks,
    int rowbase, int w, int l15, int lhi)
{
    #pragma unroll 2
    for (int ks = 0; ks < nks; ++ks) {
        bf16x8 af[4], bfr[2];
        #pragma unroll
        for (int mi = 0; mi < 4; ++mi)
            af[mi] = *(const bf16x8*)&X[(size_t)(rowbase + mi * 16 + l15) * ldx + ks * 32 + lhi * 8];
        #pragma unroll
        for (int ni = 0; ni < 2; ++ni)
            bfr[ni] = *(const bf16x8*)&WT[(size_t)(w * 32 + ni * 16 + l15) * K + k0w + ks * 32 + lhi * 8];
        #pragma unroll
        for (int mi = 0; mi < 4; ++mi)
            #pragma unroll
            for (int ni = 0; ni < 2; ++ni)
                acc[mi][ni] = __builtin_amdgcn_mfma_f32_16x16x32_bf16(
                    af[mi], bfr[ni], acc[mi][ni], 0, 0, 0);
    }
}

// GN + relu -> s.h   (call right after gn_stats; prior readers of s.h are past barrier)
__device__ __forceinline__ void epi_lds(const f32x4 acc[4][2], FSmem& s,
    const float* __restrict__ g, const float* __restrict__ b, int w, int l15, int lhi)
{
    float gv[2], bv[2];
    #pragma unroll
    for (int ni = 0; ni < 2; ++ni) {
        int col = w * 32 + ni * 16 + l15;
        gv[ni] = g[col]; bv[ni] = b[col];
    }
    #pragma unroll
    for (int mi = 0; mi < 4; ++mi)
        #pragma unroll
        for (int j = 0; j < 4; ++j) {
            int row = mi * 16 + lhi * 4 + j;
            float mean = s.mv[row][0], rstd = s.mv[row][1];
            #pragma unroll
            for (int ni = 0; ni < 2; ++ni) {
                int col = w * 32 + ni * 16 + l15;
                float val = (acc[mi][ni][j] - mean) * rstd * gv[ni] + bv[ni];
                val = fmaxf(val, 0.f);
                s.h[row * HSTR + col] = f2bf(val);
            }
        }
}

// GN in-register (no relu) -> acc overwritten with normalized values
__device__ __forceinline__ void norm_reg(f32x4 acc[4][2], const FSmem& s,
    const float* __restrict__ g, const float* __restrict__ b, int w, int l15, int lhi)
{
    float gv[2], bv[2];
    #pragma unroll
    for (int ni = 0; ni < 2; ++ni) {
        int col = w * 32 + ni * 16 + l15;
        gv[ni] = g[col]; bv[ni] = b[col];
    }
    #pragma unroll
    for (int mi = 0; mi < 4; ++mi)
        #pragma unroll
        for (int j = 0; j < 4; ++j) {
            int row = mi * 16 + lhi * 4 + j;
            float mean = s.mv[row][0], rstd = s.mv[row][1];
            #pragma unroll
            for (int ni = 0; ni < 2; ++ni)
                acc[mi][ni][j] = (acc[mi][ni][j] - mean) * rstd * gv[ni] + bv[ni];
        }
}

// ---------------------------------------------------------------------------
// input stage + first fc1, all fused
__global__ __launch_bounds__(256) void input_fused(
    const unsigned short* __restrict__ X32,       // [N+64][32] bf16
    const unsigned short* __restrict__ wts,
    const float* __restrict__ g1, const float* __restrict__ b1,
    const float* __restrict__ gt, const float* __restrict__ bt,
    const float* __restrict__ g2, const float* __restrict__ b2,
    const float* __restrict__ g1n, const float* __restrict__ b1n,
    unsigned short* __restrict__ fbf, unsigned short* __restrict__ h1bf, int nrows)
{
    __shared__ FSmem s;
    const int tid = threadIdx.x;
    const int w = tid >> 6, l = tid & 63, l15 = l & 15, lhi = l >> 4;
    const int rowbase = blockIdx.x * 64;

    const unsigned short* w1T = wts;              // K=32
    const unsigned short* wtT = wts + 4096;       // K=32
    const unsigned short* w2T = wts + 8192;       // K=128
    const unsigned short* f1T = wts + 24576;      // fc1[0], K=128

    f32x4 accA[4][2] = {}, accT[4][2] = {};
    {
        bf16x8 af[4], b1f[2], btf[2];
        #pragma unroll
        for (int mi = 0; mi < 4; ++mi)
            af[mi] = *(const bf16x8*)&X32[(size_t)(rowbase + mi * 16 + l15) * 32 + lhi * 8];
        #pragma unroll
        for (int ni = 0; ni < 2; ++ni) {
            int col = w * 32 + ni * 16 + l15;
            b1f[ni] = *(const bf16x8*)&w1T[(size_t)col * 32 + lhi * 8];
            btf[ni] = *(const bf16x8*)&wtT[(size_t)col * 32 + lhi * 8];
        }
        #pragma unroll
        for (int mi = 0; mi < 4; ++mi)
            #pragma unroll
            for (int ni = 0; ni < 2; ++ni) {
                accA[mi][ni] = __builtin_amdgcn_mfma_f32_16x16x32_bf16(af[mi], b1f[ni], accA[mi][ni], 0, 0, 0);
                accT[mi][ni] = __builtin_amdgcn_mfma_f32_16x16x32_bf16(af[mi], btf[ni], accT[mi][ni], 0, 0, 0);
            }
    }

    gn_stats(s, accT, w, l15, lhi, tid);
    norm_reg(accT, s, gt, bt, w, l15, lhi);       // T = GN(X@wt), no relu
    gn_stats(s, accA, w, l15, lhi, tid);
    epi_lds(accA, s, g1, b1, w, l15, lhi);        // h1 -> LDS
    __syncthreads();

    f32x4 accB[4][2] = {};
    gemm_lds(accB, s, w2T, 128, 0, 4, w, l15, lhi);
    gn_stats(s, accB, w, l15, lhi, tid);
    {
        float gv[2], bv[2];
        #pragma unroll
        for (int ni = 0; ni < 2; ++ni) {
            int col = w * 32 + ni * 16 + l15;
            gv[ni] = g2[col]; bv[ni] = b2[col];
        }
        #pragma unroll
        for (int mi = 0; mi < 4; ++mi)
            #pragma unroll
            for (int j = 0; j < 4; ++j) {
                int rl = mi * 16 + lhi * 4 + j;
                int row = rowbase + rl;
                float mean = s.mv[rl][0], rstd = s.mv[rl][1];
                #pragma unroll
                for (int ni = 0; ni < 2; ++ni) {
                    int col = w * 32 + ni * 16 + l15;
                    float val = (accB[mi][ni][j] - mean) * rstd * gv[ni] + bv[ni]
                              + accT[mi][ni][j];
                    val = fmaxf(val, 0.f);
                    unsigned short hv = f2bf(val);
                    s.h[rl * HSTR + col] = hv;
                    if (row < nrows) fbf[(size_t)row * NMAP + col] = hv;
                }
            }
    }
    __syncthreads();

    f32x4 accC[4][2] = {};
    gemm_lds(accC, s, f1T, 128, 0, 4, w, l15, lhi);
    gn_stats(s, accC, w, l15, lhi, tid);
    {
        float gv[2], bv[2];
        #pragma unroll
        for (int ni = 0; ni < 2; ++ni) {
            int col = w * 32 + ni * 16 + l15;
            gv[ni] = g1n[col]; bv[ni] = b1n[col];
        }
        #pragma unroll
        for (int mi = 0; mi < 4; ++mi)
            #pragma unroll
            for (int j = 0; j < 4; ++j) {
                int rl = mi * 16 + lhi * 4 + j;
                int row = rowbase + rl;
                if (row < nrows) {
                    float mean = s.mv[rl][0], rstd = s.mv[rl][1];
                    #pragma unroll
                    for (int ni = 0; ni < 2; ++ni) {
                        int col = w * 32 + ni * 16 + l15;
                        float val = (accC[mi][ni][j] - mean) * rstd * gv[ni] + bv[ni];
                        h1bf[(size_t)row * NMAP + col] = f2bf(fmaxf(val, 0.f));
                    }
                }
            }
    }
}

// ---------------------------------------------------------------------------
// one agg block WITH fused seg_max (stage 0 gathers agg into s.h):
//   agg(LDS) = segmax(h1_in); h = relu(GN([feat|agg]@fc2)); nf = relu(GN(h@lin)+feat)
//   feat <- nf; if has_next: h1_out = relu(GN(nf@fc1_next)); final: fp32 out
__global__ __launch_bounds__(256) void block_fused(
    unsigned short* __restrict__ fbf,
    const int* __restrict__ rp, const int* __restrict__ su,
    const unsigned* __restrict__ h1in,             // prev h1 (u32 view)
    const unsigned short* __restrict__ wts, int kblk,
    const float* __restrict__ g2, const float* __restrict__ b2,
    const float* __restrict__ gl, const float* __restrict__ bl,
    const float* __restrict__ g1n, const float* __restrict__ b1n,
    unsigned short* __restrict__ h1out, float* __restrict__ outf,
    int nrows, int has_next)
{
    __shared__ FSmem s;
    const int tid = threadIdx.x;
    const int w = tid >> 6, l = tid & 63, l15 = l & 15, lhi = l >> 4;
    const int rowbase = blockIdx.x * 64;

    const unsigned short* fc2T = wts + 90112 + (size_t)kblk * 32768;   // K=256
    const unsigned short* linT = wts + 221184 + (size_t)kblk * 16384;  // K=128
    const unsigned short* f1T  = wts + 24576 + (size_t)(kblk + 1) * 16384;

    // ---- stage 0: seg_max gather into s.h (agg tile, [64][128] bf16) ----
    unsigned* hU = (unsigned*)&s.h[0];
    for (int nn = w; nn < 64; nn += 4) {
        int node = rowbase + nn;
        unsigned lo0 = 0, hi0 = 0, lo1 = 0, hi1 = 0;
        if (node < nrows) {
            int s0 = rp[node], e0 = rp[node + 1];
            int j = s0;
            for (; j + 1 < e0; j += 2) {
                unsigned x0 = h1in[(size_t)su[j] * 64 + l];
                unsigned x1 = h1in[(size_t)su[j + 1] * 64 + l];
                lo0 = max(lo0, x0 & 0xffffu); hi0 = max(hi0, x0 >> 16);
                lo1 = max(lo1, x1 & 0xffffu); hi1 = max(hi1, x1 >> 16);
            }
            if (j < e0) {
                unsigned x0 = h1in[(size_t)su[j] * 64 + l];
                lo0 = max(lo0, x0 & 0xffffu); hi0 = max(hi0, x0 >> 16);
            }
            lo0 = max(lo0, lo1); hi0 = max(hi0, hi1);
        }
        hU[nn * (HSTR / 2) + l] = lo0 | (hi0 << 16);
    }
    __syncthreads();

    // ---- stage 1: h = relu(GN([feat|agg]@fc2)) ----
    f32x4 acc2[4][2] = {};
    gemm_glb(acc2, fbf, 128, 0, fc2T, 256, 4, rowbase, w, l15, lhi);
    gemm_lds(acc2, s, fc2T, 256, 128, 4, w, l15, lhi);   // agg half from LDS
    gn_stats(s, acc2, w, l15, lhi, tid);                 // 2 barriers: s.h reads done
    epi_lds(acc2, s, g2, b2, w, l15, lhi);               // overwrite s.h with h
    __syncthreads();

    // ---- stage 2: nf = relu(GN(h@lin) + feat) ----
    f32x4 acc3[4][2] = {};
    gemm_lds(acc3, s, linT, 128, 0, 4, w, l15, lhi);
    gn_stats(s, acc3, w, l15, lhi, tid);
    {
        float gv[2], bv[2];
        #pragma unroll
        for (int ni = 0; ni < 2; ++ni) {
            int col = w * 32 + ni * 16 + l15;
            gv[ni] = gl[col]; bv[ni] = bl[col];
        }
        #pragma unroll
        for (int mi = 0; mi < 4; ++mi)
            #pragma unroll
            for (int j = 0; j < 4; ++j) {
                int rl = mi * 16 + lhi * 4 + j;
                int row = rowbase + rl;
                float mean = s.mv[rl][0], rstd = s.mv[rl][1];
                #pragma unroll
                for (int ni = 0; ni < 2; ++ni) {
                    int col = w * 32 + ni * 16 + l15;
                    float val = (acc3[mi][ni][j] - mean) * rstd * gv[ni] + bv[ni];
                    if (row < nrows) val += bf2f(fbf[(size_t)row * NMAP + col]);
                    val = fmaxf(val, 0.f);
                    s.h[rl * HSTR + col] = f2bf(val);
                    if (row < nrows) {
                        if (outf) outf[(size_t)row * NMAP + col] = val;
                        else      fbf[(size_t)row * NMAP + col] = f2bf(val);
                    }
                }
            }
    }

    // ---- stage 3: h1_out = relu(GN(nf@fc1_next)) ----
    if (has_next) {
        __syncthreads();
        f32x4 acc4[4][2] = {};
        gemm_lds(acc4, s, f1T, 128, 0, 4, w, l15, lhi);
        gn_stats(s, acc4, w, l15, lhi, tid);
        float gv[2], bv[2];
        #pragma unroll
        for (int ni = 0; ni < 2; ++ni) {
            int col = w * 32 + ni * 16 + l15;
            gv[ni] = g1n[col]; bv[ni] = b1n[col];
        }
        #pragma unroll
        for (int mi = 0; mi < 4; ++mi)
            #pragma unroll
            for (int j = 0; j < 4; ++j) {
                int rl = mi * 16 + lhi * 4 + j;
                int row = rowbase + rl;
                if (row < nrows) {
                    float mean = s.mv[rl][0], rstd = s.mv[rl][1];
                    #pragma unroll
                    for (int ni = 0; ni < 2; ++ni) {
                        int col = w * 32 + ni * 16 + l15;
                        float val = (acc4[mi][ni][j] - mean) * rstd * gv[ni] + bv[ni];
                        h1out[(size_t)row * NMAP + col] = f2bf(fmaxf(val, 0.f));
                    }
                }
            }
    }
}

// ---------------------------------------------------------------------------
// all weight converts in one kernel.  wts layout (shorts):
//   w1T@0(4096) wtT@4096(4096) w2T@8192(16384) fc1T@24576(65536)
//   fc2T@90112(131072) linT@221184(65536)  total 286720
__global__ __launch_bounds__(256) void cvt_all_w(
    const float* __restrict__ in_w1, const float* __restrict__ in_wt,
    const float* __restrict__ in_w2, const float* __restrict__ fc1_w,
    const float* __restrict__ fc2_w, const float* __restrict__ lin_w,
    unsigned short* __restrict__ wts)
{
    int idx = blockIdx.x * 256 + threadIdx.x;
    if (idx >= 286720) return;
    const float* src; int off, K, Kreal;
    if (idx < 4096)        { src = in_w1; off = idx;          K = 32;  Kreal = 22; }
    else if (idx < 8192)   { src = in_wt; off = idx - 4096;   K = 32;  Kreal = 22; }
    else if (idx < 24576)  { src = in_w2; off = idx - 8192;   K = 128; Kreal = 128; }
    else if (idx < 90112)  { src = fc1_w; off = idx - 24576;  K = 128; Kreal = 128; }
    else if (idx < 221184) { src = fc2_w; off = idx - 90112;  K = 256; Kreal = 256; }
    else                   { src = lin_w; off = idx - 221184; K = 128; Kreal = 128; }
    int per = 128 * K;
    int m = off / per, rem = off - m * per;
    int c = rem / K, k = rem - c * K;
    float val = (k < Kreal) ? src[(size_t)m * per + (size_t)k * 128 + c] : 0.f;
    wts[idx] = f2bf(val);
}

// feats fp32 [N][22] -> bf16 [N+64][32] zero-padded
__global__ __launch_bounds__(256) void cvt_feats_kernel(
    const float* __restrict__ src, unsigned short* __restrict__ dst, int N)
{
    int idx = blockIdx.x * 256 + threadIdx.x;
    int n = idx >> 5, kk = idx & 31;
    if (n < N + 64) {
        float v = (n < N && kk < 22) ? src[(size_t)n * 22 + kk] : 0.f;
        dst[idx] = f2bf(v);
    }
}

// ---------------- CSR build: both scales fused per phase -------------------
__global__ __launch_bounds__(256) void hist2_kernel(
    const int* __restrict__ v, int* __restrict__ rp, int E, int N)
{
    int e = blockIdx.x * 256 + threadIdx.x;
    if (e < 2 * E) {
        int sc = e >= E;
        atomicAdd(&rp[sc * (N + 1) + v[e] + 1], 1);
    }
}

__global__ __launch_bounds__(256) void scan1_kernel(
    int* __restrict__ rp, int* __restrict__ part, int n1, int NB)
{
    __shared__ int wtot[4];
    const int sc = blockIdx.x / NB, chunk = blockIdx.x - sc * NB;
    int* data = rp + (size_t)sc * n1;
    const int tid = threadIdx.x;
    const int base = chunk * SCHUNK + tid * 8;
    int vv[8];
    #pragma unroll
    for (int i = 0; i < 8; ++i) {
        int idx = base + i;
        vv[i] = (idx < n1) ? data[idx] : 0;
    }
    #pragma unroll
    for (int i = 1; i < 8; ++i) vv[i] += vv[i - 1];
    int tsum = vv[7];
    const int lane = tid & 63, wid = tid >> 6;
    int scn = tsum;
    #pragma unroll
    for (int d = 1; d < 64; d <<= 1) {
        int t = __shfl_up(scn, d);
        if (lane >= d) scn += t;
    }
    if (lane == 63) wtot[wid] = scn;
    __syncthreads();
    int woff = 0;
    for (int w2 = 0; w2 < wid; ++w2) woff += wtot[w2];
    const int excl = scn - tsum + woff;
    #pragma unroll
    for (int i = 0; i < 8; ++i) {
        int idx = base + i;
        if (idx < n1) data[idx] = vv[i] + excl;
    }
    if (tid == 255) part[blockIdx.x] = excl + tsum;
}

__global__ __launch_bounds__(256) void scan2_kernel(int* part, int NB)
{
    __shared__ int wsum[4];
    int* data = part + blockIdx.x * NB;
    const int tid = threadIdx.x;
    const int lane = tid & 63, wid = tid >> 6;
    int carry = 0;
    for (int base = 0; base < NB; base += 256) {
        int i = base + tid;
        int val = (i < NB) ? data[i] : 0;
        #pragma unroll
        for (int d = 1; d < 64; d <<= 1) {
            int t = __shfl_up(val, d);
            if (lane >= d) val += t;
        }
        if (lane == 63) wsum[wid] = val;
        __syncthreads();
        int woff = 0;
        for (int w = 0; w < wid; ++w) woff += wsum[w];
        int total = wsum[0] + wsum[1] + wsum[2] + wsum[3];
        val += woff + carry;
        if (i < NB) data[i] = val;
        __syncthreads();
        carry += total;
    }
}

__global__ __launch_bounds__(256) void scan3_kernel(
    int* __restrict__ rp, const int* __restrict__ part, int n1, int NB)
{
    const int nbm1 = NB - 1;
    const int sc = blockIdx.x / nbm1, i = blockIdx.x - sc * nbm1;
    int* data = rp + (size_t)sc * n1;
    const int base = (i + 1) * SCHUNK + threadIdx.x * 8;
    const int off = part[sc * NB + i];
    #pragma unroll
    for (int q = 0; q < 8; ++q) {
        int idx = base + q;
        if (idx < n1) data[idx] += off;
    }
}

// gcur[bk] = sc*E + rp[sc][min(b*256, N)]   (bucket-region base in global space)
__global__ __launch_bounds__(256) void init_gcur(
    const int* __restrict__ rp, int* __restrict__ gcur, int E, int N, int nbk)
{
    int i = blockIdx.x * 256 + threadIdx.x;
    if (i < 2 * nbk) {
        int sc = i >= nbk;
        int b = i - sc * nbk;
        int nb0 = b << BKSH; if (nb0 > N) nb0 = N;
        gcur[i] = sc * E + rp[sc * (N + 1) + nb0];
    }
}

// pass 1: scatter (u,v) pairs into bucket regions (bucket = 256-node range)
__global__ __launch_bounds__(256) void bucket_scatter(
    const int* __restrict__ u, const int* __restrict__ v,
    int* __restrict__ gcur, int2* __restrict__ pairs, int E, int nbk)
{
    __shared__ int cnt[1024], base[1024];
    const int tid = threadIdx.x;
    const int tot = 2 * E;
    const int c0 = blockIdx.x * CH;
    const int nbk2 = 2 * nbk;
    for (int i = tid; i < nbk2; i += 256) cnt[i] = 0;
    __syncthreads();
    for (int i = 0; i < CH; i += 256) {
        int e = c0 + i + tid;
        if (e < tot) {
            int sc = e >= E;
            int vv = v[e];
            atomicAdd(&cnt[sc * nbk + (vv >> BKSH)], 1);
        }
    }
    __syncthreads();
    for (int i = tid; i < nbk2; i += 256) {
        int c = cnt[i];
        base[i] = c ? atomicAdd(&gcur[i], c) : 0;
        cnt[i] = 0;
    }
    __syncthreads();
    for (int i = 0; i < CH; i += 256) {
        int e = c0 + i + tid;
        if (e < tot) {
            int sc = e >= E;
            int uu = u[e], vv = v[e];
            int bk = sc * nbk + (vv >> BKSH);
            int off = atomicAdd(&cnt[bk], 1);
            pairs[(size_t)base[bk] + off] = make_int2(uu, vv);
        }
    }
}

// pass 2: per-bucket scatter into final CSR order (writes stay in ~10KB region)
__global__ __launch_bounds__(256) void bucket_fill(
    const int2* __restrict__ pairs, const int* __restrict__ rp,
    int* __restrict__ su, int E, int N, int nbk)
{
    __shared__ int curs[256];
    const int bk = blockIdx.x;
    const int sc = bk >= nbk;
    const int b = bk - sc * nbk;
    const int nb0 = b << BKSH;
    const int nb1 = min(nb0 + (1 << BKSH), N);
    const int nn = nb1 - nb0;
    const int* rps = rp + (size_t)sc * (N + 1);
    const int tid = threadIdx.x;
    const int rstart = rps[nb0], rend = rps[nb1];
    if (tid < nn) curs[tid] = rps[nb0 + tid];
    __syncthreads();
    int* sus = su + (size_t)sc * E;
    for (int idx = rstart + tid; idx < rend; idx += 256) {
        int2 pr = pairs[(size_t)sc * E + idx];
        int pos = atomicAdd(&curs[pr.y - nb0], 1);
        sus[pos] = pr.x;
    }
}

// ---------------------------------------------------------------------------
extern "C" void kernel_launch(void* const* d_in, const int* in_sizes, int n_in,
                              void* d_out, int out_size, void* d_ws, size_t ws_size,
                              hipStream_t stream)
{
    const float* feats = (const float*)d_in[0];
    const int*   u     = (const int*)d_in[1];
    const int*   v     = (const int*)d_in[2];
    const float* in_w1 = (const float*)d_in[3];
    const float* in_g1 = (const float*)d_in[4];
    const float* in_b1 = (const float*)d_in[5];
    const float* in_w2 = (const float*)d_in[6];
    const float* in_g2 = (const float*)d_in[7];
    const float* in_b2 = (const float*)d_in[8];
    const float* in_wt = (const float*)d_in[9];
    const float* in_gt = (const float*)d_in[10];
    const float* in_bt = (const float*)d_in[11];
    const float* fc1_w = (const float*)d_in[12];
    const float* fc1_g = (const float*)d_in[13];
    const float* fc1_b = (const float*)d_in[14];
    const float* fc2_w = (const float*)d_in[15];
    const float* fc2_g = (const float*)d_in[16];
    const float* fc2_b = (const float*)d_in[17];
    const float* lin_w = (const float*)d_in[18];
    const float* lin_g = (const float*)d_in[19];
    const float* lin_b = (const float*)d_in[20];

    const int N = in_sizes[0] / 22;
    const int E = in_sizes[1] / 2;
    const size_t nmp = (size_t)(N + 64) * NMAP;

    unsigned short* fbf   = (unsigned short*)d_ws;     // running feat
    unsigned short* h1A   = fbf + nmp;                 // h1 ping
    unsigned short* h1B   = h1A + nmp;                 // h1 pong (also pairs scratch)
    unsigned short* x32   = h1B + nmp;                 // padded input feats
    unsigned short* wts   = x32 + (size_t)(N + 64) * 32;
    unsigned short* wend  = wts + 286720;

    int* rp   = (int*)wend;          // 2*(N+1)
    int* su   = rp + 2 * (N + 1);    // 2*E
    int* part = su + 2 * (size_t)E;  // scan partials (<=128)
    int* gcur = part + 256;          // 2*nbk (<=1024)
    int2* pairs = (int2*)h1B;        // 16 MB; free until first block_fused stage-3

    const int nbk = (N + (1 << BKSH) - 1) >> BKSH;     // buckets per scale

    // ---- one-time converts ----
    cvt_feats_kernel<<<((N + 64) * 32 + 255) / 256, 256, 0, stream>>>(feats, x32, N);
    cvt_all_w<<<(286720 + 255) / 256, 256, 0, stream>>>(
        in_w1, in_wt, in_w2, fc1_w, fc2_w, lin_w, wts);

    // ---- one-time CSR build ----
    {
        const int n1 = N + 1;
        const int NB = (n1 + SCHUNK - 1) / SCHUNK;
        hipMemsetAsync(rp, 0, 2 * (size_t)n1 * sizeof(int), stream);
        hist2_kernel<<<(2 * E + 255) / 256, 256, 0, stream>>>(v, rp, E, N);
        scan1_kernel<<<2 * NB, 256, 0, stream>>>(rp, part, n1, NB);
        scan2_kernel<<<2, 256, 0, stream>>>(part, NB);
        scan3_kernel<<<2 * (NB - 1), 256, 0, stream>>>(rp, part, n1, NB);
        init_gcur<<<(2 * nbk + 255) / 256, 256, 0, stream>>>(rp, gcur, E, N, nbk);
        bucket_scatter<<<(2 * E + CH - 1) / CH, 256, 0, stream>>>(
            u, v, gcur, pairs, E, nbk);
        bucket_fill<<<2 * nbk, 256, 0, stream>>>(pairs, rp, su, E, N, nbk);
    }

    const int GB = (N + 63) / 64;

    // ---- input stage + fc1[0] ----
    input_fused<<<GB, 256, 0, stream>>>(x32, wts,
        in_g1, in_b1, in_gt, in_bt, in_g2, in_b2,
        fc1_g, fc1_b, fbf, h1A, N);

    // ---- agg blocks (seg_max fused; h1 ping-pongs A->B->A->B) ----
    for (int k = 0; k < 4; ++k) {
        int is = k & 1;
        int has_next = (k < 3);
        unsigned short* h1in  = (k & 1) ? h1B : h1A;
        unsigned short* h1out = (k & 1) ? h1A : h1B;
        block_fused<<<GB, 256, 0, stream>>>(fbf,
            rp + (size_t)is * (N + 1), su + (size_t)is * E,
            (const unsigned*)h1in, wts, k,
            fc2_g + k * 128, fc2_b + k * 128,
            lin_g + k * 128, lin_b + k * 128,
            has_next ? fc1_g + (k + 1) * 128 : nullptr,
            has_next ? fc1_b + (k + 1) * 128 : nullptr,
            h1out, (k == 3) ? (float*)d_out : nullptr, N, has_next);
    }
}

// Round 8
// 928.381 us; speedup vs baseline: 1.4640x; 1.4640x over previous
//
#include <hip/hip_runtime.h>

#define NMAP 128
#define EPSV 1e-5f
#define SCHUNK 2048     // elements per scan block (256 thr x 8)
#define HSTR 136        // LDS h-tile row stride in shorts (272 B)
#define BKSH 8          // 256 nodes per bucket
#define CH 8192         // edges per bucket_scatter workgroup

typedef __attribute__((ext_vector_type(8))) short bf16x8;   // 8 bf16 = 4 VGPRs
typedef __attribute__((ext_vector_type(4))) float f32x4;

__device__ __forceinline__ unsigned short f2bf(float f) {
    union { float f; unsigned u; } x; x.f = f;
    unsigned u = x.u;
    return (unsigned short)((u + 0x7fffu + ((u >> 16) & 1u)) >> 16);  // RNE
}
__device__ __forceinline__ float bf2f(unsigned short h) {
    union { unsigned u; float f; } x; x.u = ((unsigned)h) << 16;
    return x.f;
}

// ---------------------------------------------------------------------------
// Wave-strip layout: each wave owns 16 rows x 128 cols.
//   acc[ni][j]: row = lhi*4 + j (lhi = lane>>4), col = ni*16 + l15 (l15 = lane&15)
// GroupNorm reduce is fully in-wave: 8 in-thread adds + 4 shfl_xor. No barriers.

// acc += X[row0..row0+16) @ WT[kwoff..]   (A from global)
__device__ __forceinline__ void gemm_g(f32x4 acc[8],
    const unsigned short* __restrict__ X, int row0, int ldx,
    const unsigned short* __restrict__ WT, int K, int kwoff, int nks,
    int l15, int lhi)
{
    #pragma unroll
    for (int ks = 0; ks < nks; ++ks) {
        bf16x8 af = *(const bf16x8*)&X[(size_t)(row0 + l15) * ldx + ks * 32 + lhi * 8];
        #pragma unroll
        for (int ni = 0; ni < 8; ++ni) {
            bf16x8 bfr = *(const bf16x8*)&WT[(size_t)(ni * 16 + l15) * K + kwoff + ks * 32 + lhi * 8];
            acc[ni] = __builtin_amdgcn_mfma_f32_16x16x32_bf16(af, bfr, acc[ni], 0, 0, 0);
        }
    }
}

// acc += strip_lds @ WT   (A from this wave's private LDS strip, K=128)
__device__ __forceinline__ void gemm_l(f32x4 acc[8],
    const unsigned short* __restrict__ strip,     // &s.h[w*16*HSTR]
    const unsigned short* __restrict__ WT, int K,
    int l15, int lhi)
{
    #pragma unroll
    for (int ks = 0; ks < 4; ++ks) {
        bf16x8 af = *(const bf16x8*)&strip[(size_t)l15 * HSTR + ks * 32 + lhi * 8];
        #pragma unroll
        for (int ni = 0; ni < 8; ++ni) {
            bf16x8 bfr = *(const bf16x8*)&WT[(size_t)(ni * 16 + l15) * K + ks * 32 + lhi * 8];
            acc[ni] = __builtin_amdgcn_mfma_f32_16x16x32_bf16(af, bfr, acc[ni], 0, 0, 0);
        }
    }
}

// per-row mean/rstd, in-wave (rows j=0..3 of this thread's lhi group)
__device__ __forceinline__ void gn_wave(const f32x4 acc[8], float mean[4], float rstd[4])
{
    #pragma unroll
    for (int j = 0; j < 4; ++j) {
        float sm = 0.f, ss = 0.f;
        #pragma unroll
        for (int ni = 0; ni < 8; ++ni) {
            float a = acc[ni][j];
            sm += a; ss = fmaf(a, a, ss);
        }
        #pragma unroll
        for (int m = 1; m < 16; m <<= 1) {
            sm += __shfl_xor(sm, m);
            ss += __shfl_xor(ss, m);
        }
        float mu = sm * (1.f / 128.f);
        mean[j] = mu;
        rstd[j] = rsqrtf(ss * (1.f / 128.f) - mu * mu + EPSV);
    }
}

// load per-col g/b (col = ni*16 + l15)
__device__ __forceinline__ void load_gb(const float* __restrict__ g,
    const float* __restrict__ b, int l15, float gv[8], float bv[8])
{
    #pragma unroll
    for (int ni = 0; ni < 8; ++ni) { gv[ni] = g[ni * 16 + l15]; bv[ni] = b[ni * 16 + l15]; }
}

// ---------------------------------------------------------------------------
// input stage + first fc1, fused, barrier-free:
//   h1 = relu(GN(X@w1)); T = GN(X@wt); feat = relu(GN(h1@w2)+T); h1o = relu(GN(feat@fc1_0))
__global__ __launch_bounds__(256) void input_fused(
    const unsigned short* __restrict__ X32,       // [N+64][32] bf16
    const unsigned short* __restrict__ wts,
    const float* __restrict__ g1, const float* __restrict__ b1,
    const float* __restrict__ gt, const float* __restrict__ bt,
    const float* __restrict__ g2, const float* __restrict__ b2,
    const float* __restrict__ g1n, const float* __restrict__ b1n,
    unsigned short* __restrict__ fbf, unsigned short* __restrict__ h1bf, int nrows)
{
    __shared__ unsigned short sh[64 * HSTR];
    const int tid = threadIdx.x;
    const int w = tid >> 6, l = tid & 63, l15 = l & 15, lhi = l >> 4;
    const int row0 = blockIdx.x * 64 + w * 16;    // this wave's strip
    unsigned short* strip = &sh[w * 16 * HSTR];

    const unsigned short* w1T = wts;              // K=32
    const unsigned short* wtT = wts + 4096;       // K=32
    const unsigned short* w2T = wts + 8192;       // K=128
    const unsigned short* f1T = wts + 24576;      // fc1[0], K=128

    // ---- stage 0: X@w1 and X@wt (K=32, shared A-frag) ----
    f32x4 accA[8] = {}, accT[8] = {};
    {
        bf16x8 af = *(const bf16x8*)&X32[(size_t)(row0 + l15) * 32 + lhi * 8];
        #pragma unroll
        for (int ni = 0; ni < 8; ++ni) {
            bf16x8 b1f = *(const bf16x8*)&w1T[(size_t)(ni * 16 + l15) * 32 + lhi * 8];
            bf16x8 btf = *(const bf16x8*)&wtT[(size_t)(ni * 16 + l15) * 32 + lhi * 8];
            accA[ni] = __builtin_amdgcn_mfma_f32_16x16x32_bf16(af, b1f, accA[ni], 0, 0, 0);
            accT[ni] = __builtin_amdgcn_mfma_f32_16x16x32_bf16(af, btf, accT[ni], 0, 0, 0);
        }
    }

    // T = GN(X@wt) in-register (no relu)
    {
        float mn[4], rs[4], gv[8], bv[8];
        gn_wave(accT, mn, rs);
        load_gb(gt, bt, l15, gv, bv);
        #pragma unroll
        for (int ni = 0; ni < 8; ++ni)
            #pragma unroll
            for (int j = 0; j < 4; ++j)
                accT[ni][j] = (accT[ni][j] - mn[j]) * rs[j] * gv[ni] + bv[ni];
    }
    // h1 = relu(GN(X@w1)) -> strip
    {
        float mn[4], rs[4], gv[8], bv[8];
        gn_wave(accA, mn, rs);
        load_gb(g1, b1, l15, gv, bv);
        #pragma unroll
        for (int ni = 0; ni < 8; ++ni)
            #pragma unroll
            for (int j = 0; j < 4; ++j) {
                float val = fmaxf((accA[ni][j] - mn[j]) * rs[j] * gv[ni] + bv[ni], 0.f);
                strip[(lhi * 4 + j) * HSTR + ni * 16 + l15] = f2bf(val);
            }
    }

    // ---- stage 1: feat = relu(GN(h1@w2) + T) ----
    f32x4 accB[8] = {};
    gemm_l(accB, strip, w2T, 128, l15, lhi);
    {
        float mn[4], rs[4], gv[8], bv[8];
        gn_wave(accB, mn, rs);
        load_gb(g2, b2, l15, gv, bv);
        #pragma unroll
        for (int ni = 0; ni < 8; ++ni)
            #pragma unroll
            for (int j = 0; j < 4; ++j) {
                int row = row0 + lhi * 4 + j;
                float val = (accB[ni][j] - mn[j]) * rs[j] * gv[ni] + bv[ni] + accT[ni][j];
                val = fmaxf(val, 0.f);
                unsigned short hv = f2bf(val);
                strip[(lhi * 4 + j) * HSTR + ni * 16 + l15] = hv;
                if (row < nrows) fbf[(size_t)row * NMAP + ni * 16 + l15] = hv;
            }
    }

    // ---- stage 2: h1o = relu(GN(feat@fc1_0)) ----
    f32x4 accC[8] = {};
    gemm_l(accC, strip, f1T, 128, l15, lhi);
    {
        float mn[4], rs[4], gv[8], bv[8];
        gn_wave(accC, mn, rs);
        load_gb(g1n, b1n, l15, gv, bv);
        #pragma unroll
        for (int ni = 0; ni < 8; ++ni)
            #pragma unroll
            for (int j = 0; j < 4; ++j) {
                int row = row0 + lhi * 4 + j;
                if (row < nrows) {
                    float val = fmaxf((accC[ni][j] - mn[j]) * rs[j] * gv[ni] + bv[ni], 0.f);
                    h1bf[(size_t)row * NMAP + ni * 16 + l15] = f2bf(val);
                }
            }
    }
}

// ---------------------------------------------------------------------------
// one agg block (minus seg_max), barrier-free wave strips:
//   h = relu(GN([feat|agg]@fc2)); nf = relu(GN(h@lin)+feat); feat<-nf
//   if has_next: h1o = relu(GN(nf@fc1_next)); final: fp32 out
__global__ __launch_bounds__(256) void block_fused(
    unsigned short* __restrict__ fbf,
    const unsigned short* __restrict__ aggbf,
    const unsigned short* __restrict__ wts, int kblk,
    const float* __restrict__ g2, const float* __restrict__ b2,
    const float* __restrict__ gl, const float* __restrict__ bl,
    const float* __restrict__ g1n, const float* __restrict__ b1n,
    unsigned short* __restrict__ h1bf, float* __restrict__ outf,
    int nrows, int has_next)
{
    __shared__ unsigned short sh[64 * HSTR];
    const int tid = threadIdx.x;
    const int w = tid >> 6, l = tid & 63, l15 = l & 15, lhi = l >> 4;
    const int row0 = blockIdx.x * 64 + w * 16;
    unsigned short* strip = &sh[w * 16 * HSTR];

    const unsigned short* fc2T = wts + 90112 + (size_t)kblk * 32768;   // K=256
    const unsigned short* linT = wts + 221184 + (size_t)kblk * 16384;  // K=128
    const unsigned short* f1T  = wts + 24576 + (size_t)(kblk + 1) * 16384;

    // ---- stage 1: h = relu(GN([feat|agg]@fc2)) ----
    f32x4 acc2[8] = {};
    gemm_g(acc2, fbf,   row0, 128, fc2T, 256, 0,   4, l15, lhi);
    gemm_g(acc2, aggbf, row0, 128, fc2T, 256, 128, 4, l15, lhi);
    {
        float mn[4], rs[4], gv[8], bv[8];
        gn_wave(acc2, mn, rs);
        load_gb(g2, b2, l15, gv, bv);
        #pragma unroll
        for (int ni = 0; ni < 8; ++ni)
            #pragma unroll
            for (int j = 0; j < 4; ++j) {
                float val = fmaxf((acc2[ni][j] - mn[j]) * rs[j] * gv[ni] + bv[ni], 0.f);
                strip[(lhi * 4 + j) * HSTR + ni * 16 + l15] = f2bf(val);
            }
    }

    // ---- stage 2: nf = relu(GN(h@lin) + feat) ----
    f32x4 acc3[8] = {};
    gemm_l(acc3, strip, linT, 128, l15, lhi);
    {
        float mn[4], rs[4], gv[8], bv[8];
        gn_wave(acc3, mn, rs);
        load_gb(gl, bl, l15, gv, bv);
        #pragma unroll
        for (int ni = 0; ni < 8; ++ni)
            #pragma unroll
            for (int j = 0; j < 4; ++j) {
                int row = row0 + lhi * 4 + j;
                float val = (acc3[ni][j] - mn[j]) * rs[j] * gv[ni] + bv[ni];
                if (row < nrows) val += bf2f(fbf[(size_t)row * NMAP + ni * 16 + l15]);
                val = fmaxf(val, 0.f);
                strip[(lhi * 4 + j) * HSTR + ni * 16 + l15] = f2bf(val);
                if (row < nrows) {
                    if (outf) outf[(size_t)row * NMAP + ni * 16 + l15] = val;
                    else      fbf[(size_t)row * NMAP + ni * 16 + l15] = f2bf(val);
                }
            }
    }

    // ---- stage 3: h1o = relu(GN(nf@fc1_next)) ----
    if (has_next) {
        f32x4 acc4[8] = {};
        gemm_l(acc4, strip, f1T, 128, l15, lhi);
        float mn[4], rs[4], gv[8], bv[8];
        gn_wave(acc4, mn, rs);
        load_gb(g1n, b1n, l15, gv, bv);
        #pragma unroll
        for (int ni = 0; ni < 8; ++ni)
            #pragma unroll
            for (int j = 0; j < 4; ++j) {
                int row = row0 + lhi * 4 + j;
                if (row < nrows) {
                    float val = fmaxf((acc4[ni][j] - mn[j]) * rs[j] * gv[ni] + bv[ni], 0.f);
                    h1bf[(size_t)row * NMAP + ni * 16 + l15] = f2bf(val);
                }
            }
    }
}

// ---------------------------------------------------------------------------
// all weight converts in one kernel.  wts layout (shorts):
//   w1T@0(4096) wtT@4096(4096) w2T@8192(16384) fc1T@24576(65536)
//   fc2T@90112(131072) linT@221184(65536)  total 286720
__global__ __launch_bounds__(256) void cvt_all_w(
    const float* __restrict__ in_w1, const float* __restrict__ in_wt,
    const float* __restrict__ in_w2, const float* __restrict__ fc1_w,
    const float* __restrict__ fc2_w, const float* __restrict__ lin_w,
    unsigned short* __restrict__ wts)
{
    int idx = blockIdx.x * 256 + threadIdx.x;
    if (idx >= 286720) return;
    const float* src; int off, K, Kreal;
    if (idx < 4096)        { src = in_w1; off = idx;          K = 32;  Kreal = 22; }
    else if (idx < 8192)   { src = in_wt; off = idx - 4096;   K = 32;  Kreal = 22; }
    else if (idx < 24576)  { src = in_w2; off = idx - 8192;   K = 128; Kreal = 128; }
    else if (idx < 90112)  { src = fc1_w; off = idx - 24576;  K = 128; Kreal = 128; }
    else if (idx < 221184) { src = fc2_w; off = idx - 90112;  K = 256; Kreal = 256; }
    else                   { src = lin_w; off = idx - 221184; K = 128; Kreal = 128; }
    int per = 128 * K;
    int m = off / per, rem = off - m * per;
    int c = rem / K, k = rem - c * K;
    float val = (k < Kreal) ? src[(size_t)m * per + (size_t)k * 128 + c] : 0.f;
    wts[idx] = f2bf(val);
}

// feats fp32 [N][22] -> bf16 [N+64][32] zero-padded
__global__ __launch_bounds__(256) void cvt_feats_kernel(
    const float* __restrict__ src, unsigned short* __restrict__ dst, int N)
{
    int idx = blockIdx.x * 256 + threadIdx.x;
    int n = idx >> 5, kk = idx & 31;
    if (n < N + 64) {
        float v = (n < N && kk < 22) ? src[(size_t)n * 22 + kk] : 0.f;
        dst[idx] = f2bf(v);
    }
}

// ---------------- CSR build: both scales fused per phase -------------------
__global__ __launch_bounds__(256) void hist2_kernel(
    const int* __restrict__ v, int* __restrict__ rp, int E, int N)
{
    int e = blockIdx.x * 256 + threadIdx.x;
    if (e < 2 * E) {
        int sc = e >= E;
        atomicAdd(&rp[sc * (N + 1) + v[e] + 1], 1);
    }
}

__global__ __launch_bounds__(256) void scan1_kernel(
    int* __restrict__ rp, int* __restrict__ part, int n1, int NB)
{
    __shared__ int wtot[4];
    const int sc = blockIdx.x / NB, chunk = blockIdx.x - sc * NB;
    int* data = rp + (size_t)sc * n1;
    const int tid = threadIdx.x;
    const int base = chunk * SCHUNK + tid * 8;
    int vv[8];
    #pragma unroll
    for (int i = 0; i < 8; ++i) {
        int idx = base + i;
        vv[i] = (idx < n1) ? data[idx] : 0;
    }
    #pragma unroll
    for (int i = 1; i < 8; ++i) vv[i] += vv[i - 1];
    int tsum = vv[7];
    const int lane = tid & 63, wid = tid >> 6;
    int scn = tsum;
    #pragma unroll
    for (int d = 1; d < 64; d <<= 1) {
        int t = __shfl_up(scn, d);
        if (lane >= d) scn += t;
    }
    if (lane == 63) wtot[wid] = scn;
    __syncthreads();
    int woff = 0;
    for (int w2 = 0; w2 < wid; ++w2) woff += wtot[w2];
    const int excl = scn - tsum + woff;
    #pragma unroll
    for (int i = 0; i < 8; ++i) {
        int idx = base + i;
        if (idx < n1) data[idx] = vv[i] + excl;
    }
    if (tid == 255) part[blockIdx.x] = excl + tsum;
}

__global__ __launch_bounds__(256) void scan2_kernel(int* part, int NB)
{
    __shared__ int wsum[4];
    int* data = part + blockIdx.x * NB;
    const int tid = threadIdx.x;
    const int lane = tid & 63, wid = tid >> 6;
    int carry = 0;
    for (int base = 0; base < NB; base += 256) {
        int i = base + tid;
        int val = (i < NB) ? data[i] : 0;
        #pragma unroll
        for (int d = 1; d < 64; d <<= 1) {
            int t = __shfl_up(val, d);
            if (lane >= d) val += t;
        }
        if (lane == 63) wsum[wid] = val;
        __syncthreads();
        int woff = 0;
        for (int w = 0; w < wid; ++w) woff += wsum[w];
        int total = wsum[0] + wsum[1] + wsum[2] + wsum[3];
        val += woff + carry;
        if (i < NB) data[i] = val;
        __syncthreads();
        carry += total;
    }
}

__global__ __launch_bounds__(256) void scan3_kernel(
    int* __restrict__ rp, const int* __restrict__ part, int n1, int NB)
{
    const int nbm1 = NB - 1;
    const int sc = blockIdx.x / nbm1, i = blockIdx.x - sc * nbm1;
    int* data = rp + (size_t)sc * n1;
    const int base = (i + 1) * SCHUNK + threadIdx.x * 8;
    const int off = part[sc * NB + i];
    #pragma unroll
    for (int q = 0; q < 8; ++q) {
        int idx = base + q;
        if (idx < n1) data[idx] += off;
    }
}

// gcur[bk] = sc*E + rp[sc][min(b*256, N)]
__global__ __launch_bounds__(256) void init_gcur(
    const int* __restrict__ rp, int* __restrict__ gcur, int E, int N, int nbk)
{
    int i = blockIdx.x * 256 + threadIdx.x;
    if (i < 2 * nbk) {
        int sc = i >= nbk;
        int b = i - sc * nbk;
        int nb0 = b << BKSH; if (nb0 > N) nb0 = N;
        gcur[i] = sc * E + rp[sc * (N + 1) + nb0];
    }
}

// pass 1: scatter (u,v) pairs into bucket regions (bucket = 256-node range)
__global__ __launch_bounds__(256) void bucket_scatter(
    const int* __restrict__ u, const int* __restrict__ v,
    int* __restrict__ gcur, int2* __restrict__ pairs, int E, int nbk)
{
    __shared__ int cnt[1024], base[1024];
    const int tid = threadIdx.x;
    const int tot = 2 * E;
    const int c0 = blockIdx.x * CH;
    const int nbk2 = 2 * nbk;
    for (int i = tid; i < nbk2; i += 256) cnt[i] = 0;
    __syncthreads();
    for (int i = 0; i < CH; i += 256) {
        int e = c0 + i + tid;
        if (e < tot) {
            int sc = e >= E;
            int vv = v[e];
            atomicAdd(&cnt[sc * nbk + (vv >> BKSH)], 1);
        }
    }
    __syncthreads();
    for (int i = tid; i < nbk2; i += 256) {
        int c = cnt[i];
        base[i] = c ? atomicAdd(&gcur[i], c) : 0;
        cnt[i] = 0;
    }
    __syncthreads();
    for (int i = 0; i < CH; i += 256) {
        int e = c0 + i + tid;
        if (e < tot) {
            int sc = e >= E;
            int uu = u[e], vv = v[e];
            int bk = sc * nbk + (vv >> BKSH);
            int off = atomicAdd(&cnt[bk], 1);
            pairs[(size_t)base[bk] + off] = make_int2(uu, vv);
        }
    }
}

// pass 2: per-bucket scatter into final CSR order (writes stay in ~10KB region)
__global__ __launch_bounds__(256) void bucket_fill(
    const int2* __restrict__ pairs, const int* __restrict__ rp,
    int* __restrict__ su, int E, int N, int nbk)
{
    __shared__ int curs[256];
    const int bk = blockIdx.x;
    const int sc = bk >= nbk;
    const int b = bk - sc * nbk;
    const int nb0 = b << BKSH;
    const int nb1 = min(nb0 + (1 << BKSH), N);
    const int nn = nb1 - nb0;
    const int* rps = rp + (size_t)sc * (N + 1);
    const int tid = threadIdx.x;
    const int rstart = rps[nb0], rend = rps[nb1];
    if (tid < nn) curs[tid] = rps[nb0 + tid];
    __syncthreads();
    int* sus = su + (size_t)sc * E;
    for (int idx = rstart + tid; idx < rend; idx += 256) {
        int2 pr = pairs[(size_t)sc * E + idx];
        int pos = atomicAdd(&curs[pr.y - nb0], 1);
        sus[pos] = pr.x;
    }
}

// agg[n][:] = max(0, max_{j in seg n} h1[su[j]][:])  -- bf16 bitwise u16 max
__global__ __launch_bounds__(256) void seg_max_bf(
    const int* __restrict__ rp, const int* __restrict__ su,
    const unsigned* __restrict__ h1, unsigned* __restrict__ agg, int N)
{
    int node = blockIdx.x * 4 + (threadIdx.x >> 6);
    int c = threadIdx.x & 63;
    if (node >= N) return;
    int s0 = rp[node], e0 = rp[node + 1];
    unsigned lo0 = 0, hi0 = 0, lo1 = 0, hi1 = 0, lo2 = 0, hi2 = 0, lo3 = 0, hi3 = 0;
    int j = s0;
    for (; j + 3 < e0; j += 4) {
        unsigned x0 = h1[(size_t)su[j] * 64 + c];
        unsigned x1 = h1[(size_t)su[j + 1] * 64 + c];
        unsigned x2 = h1[(size_t)su[j + 2] * 64 + c];
        unsigned x3 = h1[(size_t)su[j + 3] * 64 + c];
        lo0 = max(lo0, x0 & 0xffffu); hi0 = max(hi0, x0 >> 16);
        lo1 = max(lo1, x1 & 0xffffu); hi1 = max(hi1, x1 >> 16);
        lo2 = max(lo2, x2 & 0xffffu); hi2 = max(hi2, x2 >> 16);
        lo3 = max(lo3, x3 & 0xffffu); hi3 = max(hi3, x3 >> 16);
    }
    for (; j < e0; ++j) {
        unsigned x0 = h1[(size_t)su[j] * 64 + c];
        lo0 = max(lo0, x0 & 0xffffu); hi0 = max(hi0, x0 >> 16);
    }
    lo0 = max(max(lo0, lo1), max(lo2, lo3));
    hi0 = max(max(hi0, hi1), max(hi2, hi3));
    agg[(size_t)node * 64 + c] = lo0 | (hi0 << 16);
}

// ---------------------------------------------------------------------------
extern "C" void kernel_launch(void* const* d_in, const int* in_sizes, int n_in,
                              void* d_out, int out_size, void* d_ws, size_t ws_size,
                              hipStream_t stream)
{
    const float* feats = (const float*)d_in[0];
    const int*   u     = (const int*)d_in[1];
    const int*   v     = (const int*)d_in[2];
    const float* in_w1 = (const float*)d_in[3];
    const float* in_g1 = (const float*)d_in[4];
    const float* in_b1 = (const float*)d_in[5];
    const float* in_w2 = (const float*)d_in[6];
    const float* in_g2 = (const float*)d_in[7];
    const float* in_b2 = (const float*)d_in[8];
    const float* in_wt = (const float*)d_in[9];
    const float* in_gt = (const float*)d_in[10];
    const float* in_bt = (const float*)d_in[11];
    const float* fc1_w = (const float*)d_in[12];
    const float* fc1_g = (const float*)d_in[13];
    const float* fc1_b = (const float*)d_in[14];
    const float* fc2_w = (const float*)d_in[15];
    const float* fc2_g = (const float*)d_in[16];
    const float* fc2_b = (const float*)d_in[17];
    const float* lin_w = (const float*)d_in[18];
    const float* lin_g = (const float*)d_in[19];
    const float* lin_b = (const float*)d_in[20];

    const int N = in_sizes[0] / 22;
    const int E = in_sizes[1] / 2;
    const size_t nmp = (size_t)(N + 64) * NMAP;

    unsigned short* fbf   = (unsigned short*)d_ws;     // running feat
    unsigned short* h1bf  = fbf + nmp;
    unsigned short* aggbf = h1bf + nmp;
    unsigned short* x32   = aggbf + nmp;               // padded input feats
    unsigned short* wts   = x32 + (size_t)(N + 64) * 32;
    unsigned short* wend  = wts + 286720;

    int* rp   = (int*)wend;          // 2*(N+1)
    int* su   = rp + 2 * (N + 1);    // 2*E
    int* part = su + 2 * (size_t)E;  // scan partials (<=128)
    int* gcur = part + 256;          // 2*nbk (<=1024)
    int2* pairs = (int2*)aggbf;      // 16 MB; aggbf free until first seg_max

    const int nbk = (N + (1 << BKSH) - 1) >> BKSH;     // buckets per scale

    // ---- one-time converts ----
    cvt_feats_kernel<<<((N + 64) * 32 + 255) / 256, 256, 0, stream>>>(feats, x32, N);
    cvt_all_w<<<(286720 + 255) / 256, 256, 0, stream>>>(
        in_w1, in_wt, in_w2, fc1_w, fc2_w, lin_w, wts);

    // ---- one-time CSR build ----
    {
        const int n1 = N + 1;
        const int NB = (n1 + SCHUNK - 1) / SCHUNK;
        hipMemsetAsync(rp, 0, 2 * (size_t)n1 * sizeof(int), stream);
        hist2_kernel<<<(2 * E + 255) / 256, 256, 0, stream>>>(v, rp, E, N);
        scan1_kernel<<<2 * NB, 256, 0, stream>>>(rp, part, n1, NB);
        scan2_kernel<<<2, 256, 0, stream>>>(part, NB);
        scan3_kernel<<<2 * (NB - 1), 256, 0, stream>>>(rp, part, n1, NB);
        init_gcur<<<(2 * nbk + 255) / 256, 256, 0, stream>>>(rp, gcur, E, N, nbk);
        bucket_scatter<<<(2 * E + CH - 1) / CH, 256, 0, stream>>>(
            u, v, gcur, pairs, E, nbk);
        bucket_fill<<<2 * nbk, 256, 0, stream>>>(pairs, rp, su, E, N, nbk);
    }

    const int GB = (N + 63) / 64;
    const int GS = (N + 3) / 4;

    // ---- input stage + fc1[0] ----
    input_fused<<<GB, 256, 0, stream>>>(x32, wts,
        in_g1, in_b1, in_gt, in_bt, in_g2, in_b2,
        fc1_g, fc1_b, fbf, h1bf, N);

    // ---- agg blocks ----
    for (int k = 0; k < 4; ++k) {
        int is = k & 1;
        int has_next = (k < 3);
        seg_max_bf<<<GS, 256, 0, stream>>>(rp + (size_t)is * (N + 1),
            su + (size_t)is * E, (const unsigned*)h1bf, (unsigned*)aggbf, N);
        block_fused<<<GB, 256, 0, stream>>>(fbf, aggbf, wts, k,
            fc2_g + k * 128, fc2_b + k * 128,
            lin_g + k * 128, lin_b + k * 128,
            has_next ? fc1_g + (k + 1) * 128 : nullptr,
            has_next ? fc1_b + (k + 1) * 128 : nullptr,
            h1bf, (k == 3) ? (float*)d_out : nullptr, N, has_next);
    }
}

// Round 9
// 792.705 us; speedup vs baseline: 1.7146x; 1.1712x over previous
//
#include <hip/hip_runtime.h>

#define NMAP 128
#define EPSV 1e-5f
#define SCHUNK 2048     // elements per scan block (256 thr x 8)
#define HSTR 136        // LDS h-tile row stride in shorts (272 B)
#define BKSH 8          // 256 nodes per bucket
#define CH 8192         // edges per bucket_scatter workgroup

typedef __attribute__((ext_vector_type(8))) short bf16x8;   // 8 bf16 = 4 VGPRs
typedef __attribute__((ext_vector_type(4))) float f32x4;

__device__ __forceinline__ unsigned short f2bf(float f) {
    union { float f; unsigned u; } x; x.f = f;
    unsigned u = x.u;
    return (unsigned short)((u + 0x7fffu + ((u >> 16) & 1u)) >> 16);  // RNE
}
__device__ __forceinline__ float bf2f(unsigned short h) {
    union { unsigned u; float f; } x; x.u = ((unsigned)h) << 16;
    return x.f;
}

struct __align__(16) FSmem {
    unsigned short h[64 * HSTR];    // 17408 B  bf16 h-tile [64][136]
    float red[2][16][65];           //  8320 B  GN partial sums
    float mv[64][2];                //   512 B  mean/rstd per row
};

// per-row mean/rstd over 128 cols of acc -> s.mv  (two internal barriers)
__device__ __forceinline__ void gn_stats(FSmem& s, const f32x4 acc[4][2],
                                         int w, int l15, int lhi, int tid)
{
    const int cg = w * 4 + (l15 >> 2);
    #pragma unroll
    for (int mi = 0; mi < 4; ++mi) {
        #pragma unroll
        for (int j = 0; j < 4; ++j) {
            float a0 = acc[mi][0][j], a1 = acc[mi][1][j];
            float s0 = a0 + a1, s1 = a0 * a0 + a1 * a1;
            s0 += __shfl_xor(s0, 1); s0 += __shfl_xor(s0, 2);
            s1 += __shfl_xor(s1, 1); s1 += __shfl_xor(s1, 2);
            if ((l15 & 3) == 0) {
                int row = mi * 16 + lhi * 4 + j;
                s.red[0][cg][row] = s0;
                s.red[1][cg][row] = s1;
            }
        }
    }
    __syncthreads();
    if (tid < 64) {
        float sm = 0.f, ss = 0.f;
        #pragma unroll
        for (int c2 = 0; c2 < 16; ++c2) { sm += s.red[0][c2][tid]; ss += s.red[1][c2][tid]; }
        float mean = sm * (1.f / 128.f);
        float var = ss * (1.f / 128.f) - mean * mean;
        s.mv[tid][0] = mean;
        s.mv[tid][1] = rsqrtf(var + EPSV);
    }
    __syncthreads();
}

// acc += h_lds @ WT[kwoff..]   (A from s.h cols [0,nks*32), weight K-offset kwoff)
__device__ __forceinline__ void gemm_lds(f32x4 acc[4][2], const FSmem& s,
    const unsigned short* __restrict__ WT, int K, int kwoff, int nks,
    int w, int l15, int lhi)
{
    #pragma unroll
    for (int ks = 0; ks < nks; ++ks) {
        bf16x8 af[4], bfr[2];
        #pragma unroll
        for (int mi = 0; mi < 4; ++mi)
            af[mi] = *(const bf16x8*)&s.h[(mi * 16 + l15) * HSTR + ks * 32 + lhi * 8];
        #pragma unroll
        for (int ni = 0; ni < 2; ++ni)
            bfr[ni] = *(const bf16x8*)&WT[(size_t)(w * 32 + ni * 16 + l15) * K + kwoff + ks * 32 + lhi * 8];
        #pragma unroll
        for (int mi = 0; mi < 4; ++mi)
            #pragma unroll
            for (int ni = 0; ni < 2; ++ni)
                acc[mi][ni] = __builtin_amdgcn_mfma_f32_16x16x32_bf16(
                    af[mi], bfr[ni], acc[mi][ni], 0, 0, 0);
    }
}

// acc += X[rowtile] @ WT[k0w..]   (A from global, single source)
__device__ __forceinline__ void gemm_glb(f32x4 acc[4][2],
    const unsigned short* __restrict__ X, int ldx, int k0w,
    const unsigned short* __restrict__ WT, int K, int nks,
    int rowbase, int w, int l15, int lhi)
{
    #pragma unroll 2
    for (int ks = 0; ks < nks; ++ks) {
        bf16x8 af[4], bfr[2];
        #pragma unroll
        for (int mi = 0; mi < 4; ++mi)
            af[mi] = *(const bf16x8*)&X[(size_t)(rowbase + mi * 16 + l15) * ldx + ks * 32 + lhi * 8];
        #pragma unroll
        for (int ni = 0; ni < 2; ++ni)
            bfr[ni] = *(const bf16x8*)&WT[(size_t)(w * 32 + ni * 16 + l15) * K + k0w + ks * 32 + lhi * 8];
        #pragma unroll
        for (int mi = 0; mi < 4; ++mi)
            #pragma unroll
            for (int ni = 0; ni < 2; ++ni)
                acc[mi][ni] = __builtin_amdgcn_mfma_f32_16x16x32_bf16(
                    af[mi], bfr[ni], acc[mi][ni], 0, 0, 0);
    }
}

// acc += [Xf|Xa] @ WT (K=256), both halves interleaved per k-step:
// 8 A-loads + 4 B-loads in flight before 16 MFMAs -> double outstanding mem
__device__ __forceinline__ void gemm_fc2(f32x4 acc[4][2],
    const unsigned short* __restrict__ Xf, const unsigned short* __restrict__ Xa,
    const unsigned short* __restrict__ WT,
    int rowbase, int w, int l15, int lhi)
{
    #pragma unroll
    for (int ks = 0; ks < 4; ++ks) {
        bf16x8 afF[4], afA[4], bF[2], bA[2];
        #pragma unroll
        for (int mi = 0; mi < 4; ++mi) {
            size_t ro = (size_t)(rowbase + mi * 16 + l15) * 128 + ks * 32 + lhi * 8;
            afF[mi] = *(const bf16x8*)&Xf[ro];
            afA[mi] = *(const bf16x8*)&Xa[ro];
        }
        #pragma unroll
        for (int ni = 0; ni < 2; ++ni) {
            size_t co = (size_t)(w * 32 + ni * 16 + l15) * 256 + ks * 32 + lhi * 8;
            bF[ni] = *(const bf16x8*)&WT[co];
            bA[ni] = *(const bf16x8*)&WT[co + 128];
        }
        #pragma unroll
        for (int mi = 0; mi < 4; ++mi)
            #pragma unroll
            for (int ni = 0; ni < 2; ++ni) {
                acc[mi][ni] = __builtin_amdgcn_mfma_f32_16x16x32_bf16(
                    afF[mi], bF[ni], acc[mi][ni], 0, 0, 0);
                acc[mi][ni] = __builtin_amdgcn_mfma_f32_16x16x32_bf16(
                    afA[mi], bA[ni], acc[mi][ni], 0, 0, 0);
            }
    }
}

// GN + relu -> s.h   (call right after gn_stats; prior readers of s.h are past barrier)
__device__ __forceinline__ void epi_lds(const f32x4 acc[4][2], FSmem& s,
    const float* __restrict__ g, const float* __restrict__ b, int w, int l15, int lhi)
{
    float gv[2], bv[2];
    #pragma unroll
    for (int ni = 0; ni < 2; ++ni) {
        int col = w * 32 + ni * 16 + l15;
        gv[ni] = g[col]; bv[ni] = b[col];
    }
    #pragma unroll
    for (int mi = 0; mi < 4; ++mi)
        #pragma unroll
        for (int j = 0; j < 4; ++j) {
            int row = mi * 16 + lhi * 4 + j;
            float mean = s.mv[row][0], rstd = s.mv[row][1];
            #pragma unroll
            for (int ni = 0; ni < 2; ++ni) {
                int col = w * 32 + ni * 16 + l15;
                float val = (acc[mi][ni][j] - mean) * rstd * gv[ni] + bv[ni];
                val = fmaxf(val, 0.f);
                s.h[row * HSTR + col] = f2bf(val);
            }
        }
}

// GN in-register (no relu) -> acc overwritten with normalized values
__device__ __forceinline__ void norm_reg(f32x4 acc[4][2], const FSmem& s,
    const float* __restrict__ g, const float* __restrict__ b, int w, int l15, int lhi)
{
    float gv[2], bv[2];
    #pragma unroll
    for (int ni = 0; ni < 2; ++ni) {
        int col = w * 32 + ni * 16 + l15;
        gv[ni] = g[col]; bv[ni] = b[col];
    }
    #pragma unroll
    for (int mi = 0; mi < 4; ++mi)
        #pragma unroll
        for (int j = 0; j < 4; ++j) {
            int row = mi * 16 + lhi * 4 + j;
            float mean = s.mv[row][0], rstd = s.mv[row][1];
            #pragma unroll
            for (int ni = 0; ni < 2; ++ni)
                acc[mi][ni][j] = (acc[mi][ni][j] - mean) * rstd * gv[ni] + bv[ni];
        }
}

// ---------------------------------------------------------------------------
// input stage + first fc1, all fused
__global__ __launch_bounds__(256) void input_fused(
    const unsigned short* __restrict__ X32,       // [N+64][32] bf16
    const unsigned short* __restrict__ wts,
    const float* __restrict__ g1, const float* __restrict__ b1,
    const float* __restrict__ gt, const float* __restrict__ bt,
    const float* __restrict__ g2, const float* __restrict__ b2,
    const float* __restrict__ g1n, const float* __restrict__ b1n,
    unsigned short* __restrict__ fbf, unsigned short* __restrict__ h1bf, int nrows)
{
    __shared__ FSmem s;
    const int tid = threadIdx.x;
    const int w = tid >> 6, l = tid & 63, l15 = l & 15, lhi = l >> 4;
    const int rowbase = blockIdx.x * 64;

    const unsigned short* w1T = wts;              // K=32
    const unsigned short* wtT = wts + 4096;       // K=32
    const unsigned short* w2T = wts + 8192;       // K=128
    const unsigned short* f1T = wts + 24576;      // fc1[0], K=128

    f32x4 accA[4][2] = {}, accT[4][2] = {};
    {
        bf16x8 af[4], b1f[2], btf[2];
        #pragma unroll
        for (int mi = 0; mi < 4; ++mi)
            af[mi] = *(const bf16x8*)&X32[(size_t)(rowbase + mi * 16 + l15) * 32 + lhi * 8];
        #pragma unroll
        for (int ni = 0; ni < 2; ++ni) {
            int col = w * 32 + ni * 16 + l15;
            b1f[ni] = *(const bf16x8*)&w1T[(size_t)col * 32 + lhi * 8];
            btf[ni] = *(const bf16x8*)&wtT[(size_t)col * 32 + lhi * 8];
        }
        #pragma unroll
        for (int mi = 0; mi < 4; ++mi)
            #pragma unroll
            for (int ni = 0; ni < 2; ++ni) {
                accA[mi][ni] = __builtin_amdgcn_mfma_f32_16x16x32_bf16(af[mi], b1f[ni], accA[mi][ni], 0, 0, 0);
                accT[mi][ni] = __builtin_amdgcn_mfma_f32_16x16x32_bf16(af[mi], btf[ni], accT[mi][ni], 0, 0, 0);
            }
    }

    gn_stats(s, accT, w, l15, lhi, tid);
    norm_reg(accT, s, gt, bt, w, l15, lhi);       // T = GN(X@wt), no relu
    gn_stats(s, accA, w, l15, lhi, tid);
    epi_lds(accA, s, g1, b1, w, l15, lhi);        // h1 -> LDS
    __syncthreads();

    f32x4 accB[4][2] = {};
    gemm_lds(accB, s, w2T, 128, 0, 4, w, l15, lhi);
    gn_stats(s, accB, w, l15, lhi, tid);
    {
        float gv[2], bv[2];
        #pragma unroll
        for (int ni = 0; ni < 2; ++ni) {
            int col = w * 32 + ni * 16 + l15;
            gv[ni] = g2[col]; bv[ni] = b2[col];
        }
        #pragma unroll
        for (int mi = 0; mi < 4; ++mi)
            #pragma unroll
            for (int j = 0; j < 4; ++j) {
                int rl = mi * 16 + lhi * 4 + j;
                int row = rowbase + rl;
                float mean = s.mv[rl][0], rstd = s.mv[rl][1];
                #pragma unroll
                for (int ni = 0; ni < 2; ++ni) {
                    int col = w * 32 + ni * 16 + l15;
                    float val = (accB[mi][ni][j] - mean) * rstd * gv[ni] + bv[ni]
                              + accT[mi][ni][j];
                    val = fmaxf(val, 0.f);
                    unsigned short hv = f2bf(val);
                    s.h[rl * HSTR + col] = hv;
                    if (row < nrows) fbf[(size_t)row * NMAP + col] = hv;
                }
            }
    }
    __syncthreads();

    f32x4 accC[4][2] = {};
    gemm_lds(accC, s, f1T, 128, 0, 4, w, l15, lhi);
    gn_stats(s, accC, w, l15, lhi, tid);
    {
        float gv[2], bv[2];
        #pragma unroll
        for (int ni = 0; ni < 2; ++ni) {
            int col = w * 32 + ni * 16 + l15;
            gv[ni] = g1n[col]; bv[ni] = b1n[col];
        }
        #pragma unroll
        for (int mi = 0; mi < 4; ++mi)
            #pragma unroll
            for (int j = 0; j < 4; ++j) {
                int rl = mi * 16 + lhi * 4 + j;
                int row = rowbase + rl;
                if (row < nrows) {
                    float mean = s.mv[rl][0], rstd = s.mv[rl][1];
                    #pragma unroll
                    for (int ni = 0; ni < 2; ++ni) {
                        int col = w * 32 + ni * 16 + l15;
                        float val = (accC[mi][ni][j] - mean) * rstd * gv[ni] + bv[ni];
                        h1bf[(size_t)row * NMAP + col] = f2bf(fmaxf(val, 0.f));
                    }
                }
            }
    }
}

// ---------------------------------------------------------------------------
// one agg block (minus seg_max)
__global__ __launch_bounds__(256) void block_fused(
    unsigned short* __restrict__ fbf,
    const unsigned short* __restrict__ aggbf,
    const unsigned short* __restrict__ wts, int kblk,
    const float* __restrict__ g2, const float* __restrict__ b2,
    const float* __restrict__ gl, const float* __restrict__ bl,
    const float* __restrict__ g1n, const float* __restrict__ b1n,
    unsigned short* __restrict__ h1bf, float* __restrict__ outf,
    int nrows, int has_next)
{
    __shared__ FSmem s;
    const int tid = threadIdx.x;
    const int w = tid >> 6, l = tid & 63, l15 = l & 15, lhi = l >> 4;
    const int rowbase = blockIdx.x * 64;

    const unsigned short* fc2T = wts + 90112 + (size_t)kblk * 32768;   // K=256
    const unsigned short* linT = wts + 221184 + (size_t)kblk * 16384;  // K=128
    const unsigned short* f1T  = wts + 24576 + (size_t)(kblk + 1) * 16384;

    f32x4 acc2[4][2] = {};
    gemm_fc2(acc2, fbf, aggbf, fc2T, rowbase, w, l15, lhi);
    gn_stats(s, acc2, w, l15, lhi, tid);
    epi_lds(acc2, s, g2, b2, w, l15, lhi);
    __syncthreads();

    f32x4 acc3[4][2] = {};
    gemm_lds(acc3, s, linT, 128, 0, 4, w, l15, lhi);
    gn_stats(s, acc3, w, l15, lhi, tid);
    {
        float gv[2], bv[2];
        #pragma unroll
        for (int ni = 0; ni < 2; ++ni) {
            int col = w * 32 + ni * 16 + l15;
            gv[ni] = gl[col]; bv[ni] = bl[col];
        }
        #pragma unroll
        for (int mi = 0; mi < 4; ++mi)
            #pragma unroll
            for (int j = 0; j < 4; ++j) {
                int rl = mi * 16 + lhi * 4 + j;
                int row = rowbase + rl;
                float mean = s.mv[rl][0], rstd = s.mv[rl][1];
                #pragma unroll
                for (int ni = 0; ni < 2; ++ni) {
                    int col = w * 32 + ni * 16 + l15;
                    float val = (acc3[mi][ni][j] - mean) * rstd * gv[ni] + bv[ni];
                    if (row < nrows) val += bf2f(fbf[(size_t)row * NMAP + col]);
                    val = fmaxf(val, 0.f);
                    s.h[rl * HSTR + col] = f2bf(val);
                    if (row < nrows) {
                        if (outf) outf[(size_t)row * NMAP + col] = val;
                        else      fbf[(size_t)row * NMAP + col] = f2bf(val);
                    }
                }
            }
    }

    if (has_next) {
        __syncthreads();
        f32x4 acc4[4][2] = {};
        gemm_lds(acc4, s, f1T, 128, 0, 4, w, l15, lhi);
        gn_stats(s, acc4, w, l15, lhi, tid);
        float gv[2], bv[2];
        #pragma unroll
        for (int ni = 0; ni < 2; ++ni) {
            int col = w * 32 + ni * 16 + l15;
            gv[ni] = g1n[col]; bv[ni] = b1n[col];
        }
        #pragma unroll
        for (int mi = 0; mi < 4; ++mi)
            #pragma unroll
            for (int j = 0; j < 4; ++j) {
                int rl = mi * 16 + lhi * 4 + j;
                int row = rowbase + rl;
                if (row < nrows) {
                    float mean = s.mv[rl][0], rstd = s.mv[rl][1];
                    #pragma unroll
                    for (int ni = 0; ni < 2; ++ni) {
                        int col = w * 32 + ni * 16 + l15;
                        float val = (acc4[mi][ni][j] - mean) * rstd * gv[ni] + bv[ni];
                        h1bf[(size_t)row * NMAP + col] = f2bf(fmaxf(val, 0.f));
                    }
                }
            }
    }
}

// ---------------------------------------------------------------------------
// all weight converts in one kernel.  wts layout (shorts):
//   w1T@0(4096) wtT@4096(4096) w2T@8192(16384) fc1T@24576(65536)
//   fc2T@90112(131072) linT@221184(65536)  total 286720
__global__ __launch_bounds__(256) void cvt_all_w(
    const float* __restrict__ in_w1, const float* __restrict__ in_wt,
    const float* __restrict__ in_w2, const float* __restrict__ fc1_w,
    const float* __restrict__ fc2_w, const float* __restrict__ lin_w,
    unsigned short* __restrict__ wts)
{
    int idx = blockIdx.x * 256 + threadIdx.x;
    if (idx >= 286720) return;
    const float* src; int off, K, Kreal;
    if (idx < 4096)        { src = in_w1; off = idx;          K = 32;  Kreal = 22; }
    else if (idx < 8192)   { src = in_wt; off = idx - 4096;   K = 32;  Kreal = 22; }
    else if (idx < 24576)  { src = in_w2; off = idx - 8192;   K = 128; Kreal = 128; }
    else if (idx < 90112)  { src = fc1_w; off = idx - 24576;  K = 128; Kreal = 128; }
    else if (idx < 221184) { src = fc2_w; off = idx - 90112;  K = 256; Kreal = 256; }
    else                   { src = lin_w; off = idx - 221184; K = 128; Kreal = 128; }
    int per = 128 * K;
    int m = off / per, rem = off - m * per;
    int c = rem / K, k = rem - c * K;
    float val = (k < Kreal) ? src[(size_t)m * per + (size_t)k * 128 + c] : 0.f;
    wts[idx] = f2bf(val);
}

// feats fp32 [N][22] -> bf16 [N+64][32] zero-padded
__global__ __launch_bounds__(256) void cvt_feats_kernel(
    const float* __restrict__ src, unsigned short* __restrict__ dst, int N)
{
    int idx = blockIdx.x * 256 + threadIdx.x;
    int n = idx >> 5, kk = idx & 31;
    if (n < N + 64) {
        float v = (n < N && kk < 22) ? src[(size_t)n * 22 + kk] : 0.f;
        dst[idx] = f2bf(v);
    }
}

// ---------------- CSR build: both scales fused per phase -------------------
__global__ __launch_bounds__(256) void hist2_kernel(
    const int* __restrict__ v, int* __restrict__ rp, int E, int N)
{
    int e = blockIdx.x * 256 + threadIdx.x;
    if (e < 2 * E) {
        int sc = e >= E;
        atomicAdd(&rp[sc * (N + 1) + v[e] + 1], 1);
    }
}

__global__ __launch_bounds__(256) void scan1_kernel(
    int* __restrict__ rp, int* __restrict__ part, int n1, int NB)
{
    __shared__ int wtot[4];
    const int sc = blockIdx.x / NB, chunk = blockIdx.x - sc * NB;
    int* data = rp + (size_t)sc * n1;
    const int tid = threadIdx.x;
    const int base = chunk * SCHUNK + tid * 8;
    int vv[8];
    #pragma unroll
    for (int i = 0; i < 8; ++i) {
        int idx = base + i;
        vv[i] = (idx < n1) ? data[idx] : 0;
    }
    #pragma unroll
    for (int i = 1; i < 8; ++i) vv[i] += vv[i - 1];
    int tsum = vv[7];
    const int lane = tid & 63, wid = tid >> 6;
    int scn = tsum;
    #pragma unroll
    for (int d = 1; d < 64; d <<= 1) {
        int t = __shfl_up(scn, d);
        if (lane >= d) scn += t;
    }
    if (lane == 63) wtot[wid] = scn;
    __syncthreads();
    int woff = 0;
    for (int w2 = 0; w2 < wid; ++w2) woff += wtot[w2];
    const int excl = scn - tsum + woff;
    #pragma unroll
    for (int i = 0; i < 8; ++i) {
        int idx = base + i;
        if (idx < n1) data[idx] = vv[i] + excl;
    }
    if (tid == 255) part[blockIdx.x] = excl + tsum;
}

__global__ __launch_bounds__(256) void scan2_kernel(int* part, int NB)
{
    __shared__ int wsum[4];
    int* data = part + blockIdx.x * NB;
    const int tid = threadIdx.x;
    const int lane = tid & 63, wid = tid >> 6;
    int carry = 0;
    for (int base = 0; base < NB; base += 256) {
        int i = base + tid;
        int val = (i < NB) ? data[i] : 0;
        #pragma unroll
        for (int d = 1; d < 64; d <<= 1) {
            int t = __shfl_up(val, d);
            if (lane >= d) val += t;
        }
        if (lane == 63) wsum[wid] = val;
        __syncthreads();
        int woff = 0;
        for (int w = 0; w < wid; ++w) woff += wsum[w];
        int total = wsum[0] + wsum[1] + wsum[2] + wsum[3];
        val += woff + carry;
        if (i < NB) data[i] = val;
        __syncthreads();
        carry += total;
    }
}

__global__ __launch_bounds__(256) void scan3_kernel(
    int* __restrict__ rp, const int* __restrict__ part, int n1, int NB)
{
    const int nbm1 = NB - 1;
    const int sc = blockIdx.x / nbm1, i = blockIdx.x - sc * nbm1;
    int* data = rp + (size_t)sc * n1;
    const int base = (i + 1) * SCHUNK + threadIdx.x * 8;
    const int off = part[sc * NB + i];
    #pragma unroll
    for (int q = 0; q < 8; ++q) {
        int idx = base + q;
        if (idx < n1) data[idx] += off;
    }
}

// gcur[bk] = sc*E + rp[sc][min(b*256, N)]
__global__ __launch_bounds__(256) void init_gcur(
    const int* __restrict__ rp, int* __restrict__ gcur, int E, int N, int nbk)
{
    int i = blockIdx.x * 256 + threadIdx.x;
    if (i < 2 * nbk) {
        int sc = i >= nbk;
        int b = i - sc * nbk;
        int nb0 = b << BKSH; if (nb0 > N) nb0 = N;
        gcur[i] = sc * E + rp[sc * (N + 1) + nb0];
    }
}

// pass 1: scatter (u,v) pairs into bucket regions (bucket = 256-node range)
__global__ __launch_bounds__(256) void bucket_scatter(
    const int* __restrict__ u, const int* __restrict__ v,
    int* __restrict__ gcur, int2* __restrict__ pairs, int E, int nbk)
{
    __shared__ int cnt[1024], base[1024];
    const int tid = threadIdx.x;
    const int tot = 2 * E;
    const int c0 = blockIdx.x * CH;
    const int nbk2 = 2 * nbk;
    for (int i = tid; i < nbk2; i += 256) cnt[i] = 0;
    __syncthreads();
    for (int i = 0; i < CH; i += 256) {
        int e = c0 + i + tid;
        if (e < tot) {
            int sc = e >= E;
            int vv = v[e];
            atomicAdd(&cnt[sc * nbk + (vv >> BKSH)], 1);
        }
    }
    __syncthreads();
    for (int i = tid; i < nbk2; i += 256) {
        int c = cnt[i];
        base[i] = c ? atomicAdd(&gcur[i], c) : 0;
        cnt[i] = 0;
    }
    __syncthreads();
    for (int i = 0; i < CH; i += 256) {
        int e = c0 + i + tid;
        if (e < tot) {
            int sc = e >= E;
            int uu = u[e], vv = v[e];
            int bk = sc * nbk + (vv >> BKSH);
            int off = atomicAdd(&cnt[bk], 1);
            pairs[(size_t)base[bk] + off] = make_int2(uu, vv);
        }
    }
}

// pass 2: per-bucket scatter into final CSR order (writes stay in ~10KB region)
__global__ __launch_bounds__(256) void bucket_fill(
    const int2* __restrict__ pairs, const int* __restrict__ rp,
    int* __restrict__ su, int E, int N, int nbk)
{
    __shared__ int curs[256];
    const int bk = blockIdx.x;
    const int sc = bk >= nbk;
    const int b = bk - sc * nbk;
    const int nb0 = b << BKSH;
    const int nb1 = min(nb0 + (1 << BKSH), N);
    const int nn = nb1 - nb0;
    const int* rps = rp + (size_t)sc * (N + 1);
    const int tid = threadIdx.x;
    const int rstart = rps[nb0], rend = rps[nb1];
    if (tid < nn) curs[tid] = rps[nb0 + tid];
    __syncthreads();
    int* sus = su + (size_t)sc * E;
    for (int idx = rstart + tid; idx < rend; idx += 256) {
        int2 pr = pairs[(size_t)sc * E + idx];
        int pos = atomicAdd(&curs[pr.y - nb0], 1);
        sus[pos] = pr.x;
    }
}

// agg[n][:] = max(0, max_{j in seg n} h1[su[j]][:])  -- bf16 bitwise u16 max
// 8-deep independent unroll: 8 gather rows in flight per wave
__global__ __launch_bounds__(256) void seg_max_bf(
    const int* __restrict__ rp, const int* __restrict__ su,
    const unsigned* __restrict__ h1, unsigned* __restrict__ agg, int N)
{
    int node = blockIdx.x * 4 + (threadIdx.x >> 6);
    int c = threadIdx.x & 63;
    if (node >= N) return;
    int s0 = rp[node], e0 = rp[node + 1];
    unsigned lo[8] = {0,0,0,0,0,0,0,0}, hi[8] = {0,0,0,0,0,0,0,0};
    int j = s0;
    for (; j + 7 < e0; j += 8) {
        unsigned x[8];
        #pragma unroll
        for (int q = 0; q < 8; ++q) x[q] = h1[(size_t)su[j + q] * 64 + c];
        #pragma unroll
        for (int q = 0; q < 8; ++q) {
            lo[q] = max(lo[q], x[q] & 0xffffu);
            hi[q] = max(hi[q], x[q] >> 16);
        }
    }
    for (; j < e0; ++j) {
        unsigned x0 = h1[(size_t)su[j] * 64 + c];
        lo[0] = max(lo[0], x0 & 0xffffu); hi[0] = max(hi[0], x0 >> 16);
    }
    #pragma unroll
    for (int q = 4; q > 0; q >>= 1)
        #pragma unroll
        for (int r = 0; r < q; ++r) {
            lo[r] = max(lo[r], lo[r + q]);
            hi[r] = max(hi[r], hi[r + q]);
        }
    agg[(size_t)node * 64 + c] = lo[0] | (hi[0] << 16);
}

// ---------------------------------------------------------------------------
extern "C" void kernel_launch(void* const* d_in, const int* in_sizes, int n_in,
                              void* d_out, int out_size, void* d_ws, size_t ws_size,
                              hipStream_t stream)
{
    const float* feats = (const float*)d_in[0];
    const int*   u     = (const int*)d_in[1];
    const int*   v     = (const int*)d_in[2];
    const float* in_w1 = (const float*)d_in[3];
    const float* in_g1 = (const float*)d_in[4];
    const float* in_b1 = (const float*)d_in[5];
    const float* in_w2 = (const float*)d_in[6];
    const float* in_g2 = (const float*)d_in[7];
    const float* in_b2 = (const float*)d_in[8];
    const float* in_wt = (const float*)d_in[9];
    const float* in_gt = (const float*)d_in[10];
    const float* in_bt = (const float*)d_in[11];
    const float* fc1_w = (const float*)d_in[12];
    const float* fc1_g = (const float*)d_in[13];
    const float* fc1_b = (const float*)d_in[14];
    const float* fc2_w = (const float*)d_in[15];
    const float* fc2_g = (const float*)d_in[16];
    const float* fc2_b = (const float*)d_in[17];
    const float* lin_w = (const float*)d_in[18];
    const float* lin_g = (const float*)d_in[19];
    const float* lin_b = (const float*)d_in[20];

    const int N = in_sizes[0] / 22;
    const int E = in_sizes[1] / 2;
    const size_t nmp = (size_t)(N + 64) * NMAP;

    unsigned short* fbf   = (unsigned short*)d_ws;     // running feat
    unsigned short* h1bf  = fbf + nmp;
    unsigned short* aggbf = h1bf + nmp;
    unsigned short* x32   = aggbf + nmp;               // padded input feats
    unsigned short* wts   = x32 + (size_t)(N + 64) * 32;
    unsigned short* wend  = wts + 286720;

    int* rp   = (int*)wend;          // 2*(N+1)
    int* su   = rp + 2 * (N + 1);    // 2*E
    int* part = su + 2 * (size_t)E;  // scan partials (<=128)
    int* gcur = part + 256;          // 2*nbk (<=1024)
    int2* pairs = (int2*)aggbf;      // 16 MB; aggbf free until first seg_max

    const int nbk = (N + (1 << BKSH) - 1) >> BKSH;     // buckets per scale

    // ---- one-time converts ----
    cvt_feats_kernel<<<((N + 64) * 32 + 255) / 256, 256, 0, stream>>>(feats, x32, N);
    cvt_all_w<<<(286720 + 255) / 256, 256, 0, stream>>>(
        in_w1, in_wt, in_w2, fc1_w, fc2_w, lin_w, wts);

    // ---- one-time CSR build ----
    {
        const int n1 = N + 1;
        const int NB = (n1 + SCHUNK - 1) / SCHUNK;
        hipMemsetAsync(rp, 0, 2 * (size_t)n1 * sizeof(int), stream);
        hist2_kernel<<<(2 * E + 255) / 256, 256, 0, stream>>>(v, rp, E, N);
        scan1_kernel<<<2 * NB, 256, 0, stream>>>(rp, part, n1, NB);
        scan2_kernel<<<2, 256, 0, stream>>>(part, NB);
        scan3_kernel<<<2 * (NB - 1), 256, 0, stream>>>(rp, part, n1, NB);
        init_gcur<<<(2 * nbk + 255) / 256, 256, 0, stream>>>(rp, gcur, E, N, nbk);
        bucket_scatter<<<(2 * E + CH - 1) / CH, 256, 0, stream>>>(
            u, v, gcur, pairs, E, nbk);
        bucket_fill<<<2 * nbk, 256, 0, stream>>>(pairs, rp, su, E, N, nbk);
    }

    const int GB = (N + 63) / 64;
    const int GS = (N + 3) / 4;

    // ---- input stage + fc1[0] ----
    input_fused<<<GB, 256, 0, stream>>>(x32, wts,
        in_g1, in_b1, in_gt, in_bt, in_g2, in_b2,
        fc1_g, fc1_b, fbf, h1bf, N);

    // ---- agg blocks ----
    for (int k = 0; k < 4; ++k) {
        int is = k & 1;
        int has_next = (k < 3);
        seg_max_bf<<<GS, 256, 0, stream>>>(rp + (size_t)is * (N + 1),
            su + (size_t)is * E, (const unsigned*)h1bf, (unsigned*)aggbf, N);
        block_fused<<<GB, 256, 0, stream>>>(fbf, aggbf, wts, k,
            fc2_g + k * 128, fc2_b + k * 128,
            lin_g + k * 128, lin_b + k * 128,
            has_next ? fc1_g + (k + 1) * 128 : nullptr,
            has_next ? fc1_b + (k + 1) * 128 : nullptr,
            h1bf, (k == 3) ? (float*)d_out : nullptr, N, has_next);
    }
}

// Round 10
// 779.040 us; speedup vs baseline: 1.7447x; 1.0175x over previous
//
#include <hip/hip_runtime.h>

#define NMAP 128
#define EPSV 1e-5f
#define SCHUNK 2048     // elements per scan block (256 thr x 8)
#define HSTR 136        // LDS h-tile row stride in shorts (272 B)
#define BKSH 8          // 256 nodes per bucket
#define CH 8192         // edges per bucket_scatter workgroup

typedef __attribute__((ext_vector_type(8))) short bf16x8;   // 8 bf16 = 4 VGPRs
typedef __attribute__((ext_vector_type(4))) float f32x4;

__device__ __forceinline__ unsigned short f2bf(float f) {
    union { float f; unsigned u; } x; x.f = f;
    unsigned u = x.u;
    return (unsigned short)((u + 0x7fffu + ((u >> 16) & 1u)) >> 16);  // RNE
}
__device__ __forceinline__ float bf2f(unsigned short h) {
    union { unsigned u; float f; } x; x.u = ((unsigned)h) << 16;
    return x.f;
}

// M=32 tile: 4 waves; wave w -> cols [w*32,(w+1)*32), 2x2 fragments.
// row = mi*16 + lhi*4 + j (mi<2), col = w*32 + ni*16 + l15 (ni<2).
struct __align__(16) FSmem {
    unsigned short h[32 * HSTR];    // 8704 B  bf16 h-tile [32][136]
    float red[2][4][36];            // 1152 B  per-wave GN partials
    float mv[32][2];                //  256 B  mean/rstd per row
};

// per-row mean/rstd over 128 cols -> s.mv  (full in-wave 16-lane reduce first)
__device__ __forceinline__ void gn_stats(FSmem& s, const f32x4 acc[2][2],
                                         int w, int l15, int lhi, int tid)
{
    #pragma unroll
    for (int mi = 0; mi < 2; ++mi) {
        #pragma unroll
        for (int j = 0; j < 4; ++j) {
            float a0 = acc[mi][0][j], a1 = acc[mi][1][j];
            float s0 = a0 + a1, s1 = a0 * a0 + a1 * a1;
            #pragma unroll
            for (int m = 1; m < 16; m <<= 1) {
                s0 += __shfl_xor(s0, m);
                s1 += __shfl_xor(s1, m);
            }
            if (l15 == 0) {
                int row = mi * 16 + lhi * 4 + j;
                s.red[0][w][row] = s0;
                s.red[1][w][row] = s1;
            }
        }
    }
    __syncthreads();
    if (tid < 32) {
        float sm = 0.f, ss = 0.f;
        #pragma unroll
        for (int ww = 0; ww < 4; ++ww) { sm += s.red[0][ww][tid]; ss += s.red[1][ww][tid]; }
        float mean = sm * (1.f / 128.f);
        float var = ss * (1.f / 128.f) - mean * mean;
        s.mv[tid][0] = mean;
        s.mv[tid][1] = rsqrtf(var + EPSV);
    }
    __syncthreads();
}

// acc += h_lds @ WT[kwoff..]   (A from s.h)
__device__ __forceinline__ void gemm_lds(f32x4 acc[2][2], const FSmem& s,
    const unsigned short* __restrict__ WT, int K, int kwoff, int nks,
    int w, int l15, int lhi)
{
    #pragma unroll
    for (int ks = 0; ks < nks; ++ks) {
        bf16x8 af[2], bfr[2];
        #pragma unroll
        for (int mi = 0; mi < 2; ++mi)
            af[mi] = *(const bf16x8*)&s.h[(mi * 16 + l15) * HSTR + ks * 32 + lhi * 8];
        #pragma unroll
        for (int ni = 0; ni < 2; ++ni)
            bfr[ni] = *(const bf16x8*)&WT[(size_t)(w * 32 + ni * 16 + l15) * K + kwoff + ks * 32 + lhi * 8];
        #pragma unroll
        for (int mi = 0; mi < 2; ++mi)
            #pragma unroll
            for (int ni = 0; ni < 2; ++ni)
                acc[mi][ni] = __builtin_amdgcn_mfma_f32_16x16x32_bf16(
                    af[mi], bfr[ni], acc[mi][ni], 0, 0, 0);
    }
}

// acc += [Xf|Xa] @ WT (K=256), halves interleaved per k-step
__device__ __forceinline__ void gemm_fc2(f32x4 acc[2][2],
    const unsigned short* __restrict__ Xf, const unsigned short* __restrict__ Xa,
    const unsigned short* __restrict__ WT,
    int rowbase, int w, int l15, int lhi)
{
    #pragma unroll
    for (int ks = 0; ks < 4; ++ks) {
        bf16x8 afF[2], afA[2], bF[2], bA[2];
        #pragma unroll
        for (int mi = 0; mi < 2; ++mi) {
            size_t ro = (size_t)(rowbase + mi * 16 + l15) * 128 + ks * 32 + lhi * 8;
            afF[mi] = *(const bf16x8*)&Xf[ro];
            afA[mi] = *(const bf16x8*)&Xa[ro];
        }
        #pragma unroll
        for (int ni = 0; ni < 2; ++ni) {
            size_t co = (size_t)(w * 32 + ni * 16 + l15) * 256 + ks * 32 + lhi * 8;
            bF[ni] = *(const bf16x8*)&WT[co];
            bA[ni] = *(const bf16x8*)&WT[co + 128];
        }
        #pragma unroll
        for (int mi = 0; mi < 2; ++mi)
            #pragma unroll
            for (int ni = 0; ni < 2; ++ni) {
                acc[mi][ni] = __builtin_amdgcn_mfma_f32_16x16x32_bf16(
                    afF[mi], bF[ni], acc[mi][ni], 0, 0, 0);
                acc[mi][ni] = __builtin_amdgcn_mfma_f32_16x16x32_bf16(
                    afA[mi], bA[ni], acc[mi][ni], 0, 0, 0);
            }
    }
}

// GN + relu -> s.h
__device__ __forceinline__ void epi_lds(const f32x4 acc[2][2], FSmem& s,
    const float* __restrict__ g, const float* __restrict__ b, int w, int l15, int lhi)
{
    float gv[2], bv[2];
    #pragma unroll
    for (int ni = 0; ni < 2; ++ni) {
        int col = w * 32 + ni * 16 + l15;
        gv[ni] = g[col]; bv[ni] = b[col];
    }
    #pragma unroll
    for (int mi = 0; mi < 2; ++mi)
        #pragma unroll
        for (int j = 0; j < 4; ++j) {
            int row = mi * 16 + lhi * 4 + j;
            float mean = s.mv[row][0], rstd = s.mv[row][1];
            #pragma unroll
            for (int ni = 0; ni < 2; ++ni) {
                int col = w * 32 + ni * 16 + l15;
                float val = (acc[mi][ni][j] - mean) * rstd * gv[ni] + bv[ni];
                val = fmaxf(val, 0.f);
                s.h[row * HSTR + col] = f2bf(val);
            }
        }
}

// GN in-register (no relu)
__device__ __forceinline__ void norm_reg(f32x4 acc[2][2], const FSmem& s,
    const float* __restrict__ g, const float* __restrict__ b, int w, int l15, int lhi)
{
    float gv[2], bv[2];
    #pragma unroll
    for (int ni = 0; ni < 2; ++ni) {
        int col = w * 32 + ni * 16 + l15;
        gv[ni] = g[col]; bv[ni] = b[col];
    }
    #pragma unroll
    for (int mi = 0; mi < 2; ++mi)
        #pragma unroll
        for (int j = 0; j < 4; ++j) {
            int row = mi * 16 + lhi * 4 + j;
            float mean = s.mv[row][0], rstd = s.mv[row][1];
            #pragma unroll
            for (int ni = 0; ni < 2; ++ni)
                acc[mi][ni][j] = (acc[mi][ni][j] - mean) * rstd * gv[ni] + bv[ni];
        }
}

// ---------------------------------------------------------------------------
// input stage + first fc1, all fused (M=32 tile)
__global__ __launch_bounds__(256) void input_fused(
    const unsigned short* __restrict__ X32,       // [N+64][32] bf16
    const unsigned short* __restrict__ wts,
    const float* __restrict__ g1, const float* __restrict__ b1,
    const float* __restrict__ gt, const float* __restrict__ bt,
    const float* __restrict__ g2, const float* __restrict__ b2,
    const float* __restrict__ g1n, const float* __restrict__ b1n,
    unsigned short* __restrict__ fbf, unsigned short* __restrict__ h1bf, int nrows)
{
    __shared__ FSmem s;
    const int tid = threadIdx.x;
    const int w = tid >> 6, l = tid & 63, l15 = l & 15, lhi = l >> 4;
    const int rowbase = blockIdx.x * 32;

    const unsigned short* w1T = wts;              // K=32
    const unsigned short* wtT = wts + 4096;       // K=32
    const unsigned short* w2T = wts + 8192;       // K=128
    const unsigned short* f1T = wts + 24576;      // fc1[0], K=128

    f32x4 accA[2][2] = {}, accT[2][2] = {};
    {
        bf16x8 af[2], b1f[2], btf[2];
        #pragma unroll
        for (int mi = 0; mi < 2; ++mi)
            af[mi] = *(const bf16x8*)&X32[(size_t)(rowbase + mi * 16 + l15) * 32 + lhi * 8];
        #pragma unroll
        for (int ni = 0; ni < 2; ++ni) {
            int col = w * 32 + ni * 16 + l15;
            b1f[ni] = *(const bf16x8*)&w1T[(size_t)col * 32 + lhi * 8];
            btf[ni] = *(const bf16x8*)&wtT[(size_t)col * 32 + lhi * 8];
        }
        #pragma unroll
        for (int mi = 0; mi < 2; ++mi)
            #pragma unroll
            for (int ni = 0; ni < 2; ++ni) {
                accA[mi][ni] = __builtin_amdgcn_mfma_f32_16x16x32_bf16(af[mi], b1f[ni], accA[mi][ni], 0, 0, 0);
                accT[mi][ni] = __builtin_amdgcn_mfma_f32_16x16x32_bf16(af[mi], btf[ni], accT[mi][ni], 0, 0, 0);
            }
    }

    gn_stats(s, accT, w, l15, lhi, tid);
    norm_reg(accT, s, gt, bt, w, l15, lhi);       // T = GN(X@wt), no relu
    gn_stats(s, accA, w, l15, lhi, tid);
    epi_lds(accA, s, g1, b1, w, l15, lhi);        // h1 -> LDS
    __syncthreads();

    f32x4 accB[2][2] = {};
    gemm_lds(accB, s, w2T, 128, 0, 4, w, l15, lhi);
    gn_stats(s, accB, w, l15, lhi, tid);
    {
        float gv[2], bv[2];
        #pragma unroll
        for (int ni = 0; ni < 2; ++ni) {
            int col = w * 32 + ni * 16 + l15;
            gv[ni] = g2[col]; bv[ni] = b2[col];
        }
        #pragma unroll
        for (int mi = 0; mi < 2; ++mi)
            #pragma unroll
            for (int j = 0; j < 4; ++j) {
                int rl = mi * 16 + lhi * 4 + j;
                int row = rowbase + rl;
                float mean = s.mv[rl][0], rstd = s.mv[rl][1];
                #pragma unroll
                for (int ni = 0; ni < 2; ++ni) {
                    int col = w * 32 + ni * 16 + l15;
                    float val = (accB[mi][ni][j] - mean) * rstd * gv[ni] + bv[ni]
                              + accT[mi][ni][j];
                    val = fmaxf(val, 0.f);
                    unsigned short hv = f2bf(val);
                    s.h[rl * HSTR + col] = hv;
                    if (row < nrows) fbf[(size_t)row * NMAP + col] = hv;
                }
            }
    }
    __syncthreads();

    f32x4 accC[2][2] = {};
    gemm_lds(accC, s, f1T, 128, 0, 4, w, l15, lhi);
    gn_stats(s, accC, w, l15, lhi, tid);
    {
        float gv[2], bv[2];
        #pragma unroll
        for (int ni = 0; ni < 2; ++ni) {
            int col = w * 32 + ni * 16 + l15;
            gv[ni] = g1n[col]; bv[ni] = b1n[col];
        }
        #pragma unroll
        for (int mi = 0; mi < 2; ++mi)
            #pragma unroll
            for (int j = 0; j < 4; ++j) {
                int rl = mi * 16 + lhi * 4 + j;
                int row = rowbase + rl;
                if (row < nrows) {
                    float mean = s.mv[rl][0], rstd = s.mv[rl][1];
                    #pragma unroll
                    for (int ni = 0; ni < 2; ++ni) {
                        int col = w * 32 + ni * 16 + l15;
                        float val = (accC[mi][ni][j] - mean) * rstd * gv[ni] + bv[ni];
                        h1bf[(size_t)row * NMAP + col] = f2bf(fmaxf(val, 0.f));
                    }
                }
            }
    }
}

// ---------------------------------------------------------------------------
// one agg block (minus seg_max), M=32 tile
__global__ __launch_bounds__(256) void block_fused(
    unsigned short* __restrict__ fbf,
    const unsigned short* __restrict__ aggbf,
    const unsigned short* __restrict__ wts, int kblk,
    const float* __restrict__ g2, const float* __restrict__ b2,
    const float* __restrict__ gl, const float* __restrict__ bl,
    const float* __restrict__ g1n, const float* __restrict__ b1n,
    unsigned short* __restrict__ h1bf, float* __restrict__ outf,
    int nrows, int has_next)
{
    __shared__ FSmem s;
    const int tid = threadIdx.x;
    const int w = tid >> 6, l = tid & 63, l15 = l & 15, lhi = l >> 4;
    const int rowbase = blockIdx.x * 32;

    const unsigned short* fc2T = wts + 90112 + (size_t)kblk * 32768;   // K=256
    const unsigned short* linT = wts + 221184 + (size_t)kblk * 16384;  // K=128
    const unsigned short* f1T  = wts + 24576 + (size_t)(kblk + 1) * 16384;

    f32x4 acc2[2][2] = {};
    gemm_fc2(acc2, fbf, aggbf, fc2T, rowbase, w, l15, lhi);
    gn_stats(s, acc2, w, l15, lhi, tid);
    epi_lds(acc2, s, g2, b2, w, l15, lhi);
    __syncthreads();

    f32x4 acc3[2][2] = {};
    gemm_lds(acc3, s, linT, 128, 0, 4, w, l15, lhi);
    gn_stats(s, acc3, w, l15, lhi, tid);
    {
        float gv[2], bv[2];
        #pragma unroll
        for (int ni = 0; ni < 2; ++ni) {
            int col = w * 32 + ni * 16 + l15;
            gv[ni] = gl[col]; bv[ni] = bl[col];
        }
        #pragma unroll
        for (int mi = 0; mi < 2; ++mi)
            #pragma unroll
            for (int j = 0; j < 4; ++j) {
                int rl = mi * 16 + lhi * 4 + j;
                int row = rowbase + rl;
                float mean = s.mv[rl][0], rstd = s.mv[rl][1];
                #pragma unroll
                for (int ni = 0; ni < 2; ++ni) {
                    int col = w * 32 + ni * 16 + l15;
                    float val = (acc3[mi][ni][j] - mean) * rstd * gv[ni] + bv[ni];
                    if (row < nrows) val += bf2f(fbf[(size_t)row * NMAP + col]);
                    val = fmaxf(val, 0.f);
                    s.h[rl * HSTR + col] = f2bf(val);
                    if (row < nrows) {
                        if (outf) outf[(size_t)row * NMAP + col] = val;
                        else      fbf[(size_t)row * NMAP + col] = f2bf(val);
                    }
                }
            }
    }

    if (has_next) {
        __syncthreads();
        f32x4 acc4[2][2] = {};
        gemm_lds(acc4, s, f1T, 128, 0, 4, w, l15, lhi);
        gn_stats(s, acc4, w, l15, lhi, tid);
        float gv[2], bv[2];
        #pragma unroll
        for (int ni = 0; ni < 2; ++ni) {
            int col = w * 32 + ni * 16 + l15;
            gv[ni] = g1n[col]; bv[ni] = b1n[col];
        }
        #pragma unroll
        for (int mi = 0; mi < 2; ++mi)
            #pragma unroll
            for (int j = 0; j < 4; ++j) {
                int rl = mi * 16 + lhi * 4 + j;
                int row = rowbase + rl;
                if (row < nrows) {
                    float mean = s.mv[rl][0], rstd = s.mv[rl][1];
                    #pragma unroll
                    for (int ni = 0; ni < 2; ++ni) {
                        int col = w * 32 + ni * 16 + l15;
                        float val = (acc4[mi][ni][j] - mean) * rstd * gv[ni] + bv[ni];
                        h1bf[(size_t)row * NMAP + col] = f2bf(fmaxf(val, 0.f));
                    }
                }
            }
    }
}

// ---------------------------------------------------------------------------
// all weight converts in one kernel.  wts layout (shorts):
//   w1T@0(4096) wtT@4096(4096) w2T@8192(16384) fc1T@24576(65536)
//   fc2T@90112(131072) linT@221184(65536)  total 286720
__global__ __launch_bounds__(256) void cvt_all_w(
    const float* __restrict__ in_w1, const float* __restrict__ in_wt,
    const float* __restrict__ in_w2, const float* __restrict__ fc1_w,
    const float* __restrict__ fc2_w, const float* __restrict__ lin_w,
    unsigned short* __restrict__ wts)
{
    int idx = blockIdx.x * 256 + threadIdx.x;
    if (idx >= 286720) return;
    const float* src; int off, K, Kreal;
    if (idx < 4096)        { src = in_w1; off = idx;          K = 32;  Kreal = 22; }
    else if (idx < 8192)   { src = in_wt; off = idx - 4096;   K = 32;  Kreal = 22; }
    else if (idx < 24576)  { src = in_w2; off = idx - 8192;   K = 128; Kreal = 128; }
    else if (idx < 90112)  { src = fc1_w; off = idx - 24576;  K = 128; Kreal = 128; }
    else if (idx < 221184) { src = fc2_w; off = idx - 90112;  K = 256; Kreal = 256; }
    else                   { src = lin_w; off = idx - 221184; K = 128; Kreal = 128; }
    int per = 128 * K;
    int m = off / per, rem = off - m * per;
    int c = rem / K, k = rem - c * K;
    float val = (k < Kreal) ? src[(size_t)m * per + (size_t)k * 128 + c] : 0.f;
    wts[idx] = f2bf(val);
}

// feats fp32 [N][22] -> bf16 [N+64][32] zero-padded
__global__ __launch_bounds__(256) void cvt_feats_kernel(
    const float* __restrict__ src, unsigned short* __restrict__ dst, int N)
{
    int idx = blockIdx.x * 256 + threadIdx.x;
    int n = idx >> 5, kk = idx & 31;
    if (n < N + 64) {
        float v = (n < N && kk < 22) ? src[(size_t)n * 22 + kk] : 0.f;
        dst[idx] = f2bf(v);
    }
}

// ---------------- CSR build: both scales fused per phase -------------------
__global__ __launch_bounds__(256) void hist2_kernel(
    const int* __restrict__ v, int* __restrict__ rp, int E, int N)
{
    int e = blockIdx.x * 256 + threadIdx.x;
    if (e < 2 * E) {
        int sc = e >= E;
        atomicAdd(&rp[sc * (N + 1) + v[e] + 1], 1);
    }
}

__global__ __launch_bounds__(256) void scan1_kernel(
    int* __restrict__ rp, int* __restrict__ part, int n1, int NB)
{
    __shared__ int wtot[4];
    const int sc = blockIdx.x / NB, chunk = blockIdx.x - sc * NB;
    int* data = rp + (size_t)sc * n1;
    const int tid = threadIdx.x;
    const int base = chunk * SCHUNK + tid * 8;
    int vv[8];
    #pragma unroll
    for (int i = 0; i < 8; ++i) {
        int idx = base + i;
        vv[i] = (idx < n1) ? data[idx] : 0;
    }
    #pragma unroll
    for (int i = 1; i < 8; ++i) vv[i] += vv[i - 1];
    int tsum = vv[7];
    const int lane = tid & 63, wid = tid >> 6;
    int scn = tsum;
    #pragma unroll
    for (int d = 1; d < 64; d <<= 1) {
        int t = __shfl_up(scn, d);
        if (lane >= d) scn += t;
    }
    if (lane == 63) wtot[wid] = scn;
    __syncthreads();
    int woff = 0;
    for (int w2 = 0; w2 < wid; ++w2) woff += wtot[w2];
    const int excl = scn - tsum + woff;
    #pragma unroll
    for (int i = 0; i < 8; ++i) {
        int idx = base + i;
        if (idx < n1) data[idx] = vv[i] + excl;
    }
    if (tid == 255) part[blockIdx.x] = excl + tsum;
}

__global__ __launch_bounds__(256) void scan2_kernel(int* part, int NB)
{
    __shared__ int wsum[4];
    int* data = part + blockIdx.x * NB;
    const int tid = threadIdx.x;
    const int lane = tid & 63, wid = tid >> 6;
    int carry = 0;
    for (int base = 0; base < NB; base += 256) {
        int i = base + tid;
        int val = (i < NB) ? data[i] : 0;
        #pragma unroll
        for (int d = 1; d < 64; d <<= 1) {
            int t = __shfl_up(val, d);
            if (lane >= d) val += t;
        }
        if (lane == 63) wsum[wid] = val;
        __syncthreads();
        int woff = 0;
        for (int w = 0; w < wid; ++w) woff += wsum[w];
        int total = wsum[0] + wsum[1] + wsum[2] + wsum[3];
        val += woff + carry;
        if (i < NB) data[i] = val;
        __syncthreads();
        carry += total;
    }
}

__global__ __launch_bounds__(256) void scan3_kernel(
    int* __restrict__ rp, const int* __restrict__ part, int n1, int NB)
{
    const int nbm1 = NB - 1;
    const int sc = blockIdx.x / nbm1, i = blockIdx.x - sc * nbm1;
    int* data = rp + (size_t)sc * n1;
    const int base = (i + 1) * SCHUNK + threadIdx.x * 8;
    const int off = part[sc * NB + i];
    #pragma unroll
    for (int q = 0; q < 8; ++q) {
        int idx = base + q;
        if (idx < n1) data[idx] += off;
    }
}

// gcur[bk] = sc*E + rp[sc][min(b*256, N)]
__global__ __launch_bounds__(256) void init_gcur(
    const int* __restrict__ rp, int* __restrict__ gcur, int E, int N, int nbk)
{
    int i = blockIdx.x * 256 + threadIdx.x;
    if (i < 2 * nbk) {
        int sc = i >= nbk;
        int b = i - sc * nbk;
        int nb0 = b << BKSH; if (nb0 > N) nb0 = N;
        gcur[i] = sc * E + rp[sc * (N + 1) + nb0];
    }
}

// pass 1: scatter (u,v) pairs into bucket regions (bucket = 256-node range)
__global__ __launch_bounds__(256) void bucket_scatter(
    const int* __restrict__ u, const int* __restrict__ v,
    int* __restrict__ gcur, int2* __restrict__ pairs, int E, int nbk)
{
    __shared__ int cnt[1024], base[1024];
    const int tid = threadIdx.x;
    const int tot = 2 * E;
    const int c0 = blockIdx.x * CH;
    const int nbk2 = 2 * nbk;
    for (int i = tid; i < nbk2; i += 256) cnt[i] = 0;
    __syncthreads();
    for (int i = 0; i < CH; i += 256) {
        int e = c0 + i + tid;
        if (e < tot) {
            int sc = e >= E;
            int vv = v[e];
            atomicAdd(&cnt[sc * nbk + (vv >> BKSH)], 1);
        }
    }
    __syncthreads();
    for (int i = tid; i < nbk2; i += 256) {
        int c = cnt[i];
        base[i] = c ? atomicAdd(&gcur[i], c) : 0;
        cnt[i] = 0;
    }
    __syncthreads();
    for (int i = 0; i < CH; i += 256) {
        int e = c0 + i + tid;
        if (e < tot) {
            int sc = e >= E;
            int uu = u[e], vv = v[e];
            int bk = sc * nbk + (vv >> BKSH);
            int off = atomicAdd(&cnt[bk], 1);
            pairs[(size_t)base[bk] + off] = make_int2(uu, vv);
        }
    }
}

// pass 2: per-bucket scatter into final CSR order (writes stay in ~10KB region)
__global__ __launch_bounds__(256) void bucket_fill(
    const int2* __restrict__ pairs, const int* __restrict__ rp,
    int* __restrict__ su, int E, int N, int nbk)
{
    __shared__ int curs[256];
    const int bk = blockIdx.x;
    const int sc = bk >= nbk;
    const int b = bk - sc * nbk;
    const int nb0 = b << BKSH;
    const int nb1 = min(nb0 + (1 << BKSH), N);
    const int nn = nb1 - nb0;
    const int* rps = rp + (size_t)sc * (N + 1);
    const int tid = threadIdx.x;
    const int rstart = rps[nb0], rend = rps[nb1];
    if (tid < nn) curs[tid] = rps[nb0 + tid];
    __syncthreads();
    int* sus = su + (size_t)sc * E;
    for (int idx = rstart + tid; idx < rend; idx += 256) {
        int2 pr = pairs[(size_t)sc * E + idx];
        int pos = atomicAdd(&curs[pr.y - nb0], 1);
        sus[pos] = pr.x;
    }
}

// agg[n][:] = max(0, max_{j in seg n} h1[su[j]][:])  -- bf16 bitwise u16 max
// 8-deep independent unroll: 8 gather rows in flight per wave
__global__ __launch_bounds__(256) void seg_max_bf(
    const int* __restrict__ rp, const int* __restrict__ su,
    const unsigned* __restrict__ h1, unsigned* __restrict__ agg, int N)
{
    int node = blockIdx.x * 4 + (threadIdx.x >> 6);
    int c = threadIdx.x & 63;
    if (node >= N) return;
    int s0 = rp[node], e0 = rp[node + 1];
    unsigned lo[8] = {0,0,0,0,0,0,0,0}, hi[8] = {0,0,0,0,0,0,0,0};
    int j = s0;
    for (; j + 7 < e0; j += 8) {
        unsigned x[8];
        #pragma unroll
        for (int q = 0; q < 8; ++q) x[q] = h1[(size_t)su[j + q] * 64 + c];
        #pragma unroll
        for (int q = 0; q < 8; ++q) {
            lo[q] = max(lo[q], x[q] & 0xffffu);
            hi[q] = max(hi[q], x[q] >> 16);
        }
    }
    for (; j < e0; ++j) {
        unsigned x0 = h1[(size_t)su[j] * 64 + c];
        lo[0] = max(lo[0], x0 & 0xffffu); hi[0] = max(hi[0], x0 >> 16);
    }
    #pragma unroll
    for (int q = 4; q > 0; q >>= 1)
        #pragma unroll
        for (int r = 0; r < q; ++r) {
            lo[r] = max(lo[r], lo[r + q]);
            hi[r] = max(hi[r], hi[r + q]);
        }
    agg[(size_t)node * 64 + c] = lo[0] | (hi[0] << 16);
}

// ---------------------------------------------------------------------------
extern "C" void kernel_launch(void* const* d_in, const int* in_sizes, int n_in,
                              void* d_out, int out_size, void* d_ws, size_t ws_size,
                              hipStream_t stream)
{
    const float* feats = (const float*)d_in[0];
    const int*   u     = (const int*)d_in[1];
    const int*   v     = (const int*)d_in[2];
    const float* in_w1 = (const float*)d_in[3];
    const float* in_g1 = (const float*)d_in[4];
    const float* in_b1 = (const float*)d_in[5];
    const float* in_w2 = (const float*)d_in[6];
    const float* in_g2 = (const float*)d_in[7];
    const float* in_b2 = (const float*)d_in[8];
    const float* in_wt = (const float*)d_in[9];
    const float* in_gt = (const float*)d_in[10];
    const float* in_bt = (const float*)d_in[11];
    const float* fc1_w = (const float*)d_in[12];
    const float* fc1_g = (const float*)d_in[13];
    const float* fc1_b = (const float*)d_in[14];
    const float* fc2_w = (const float*)d_in[15];
    const float* fc2_g = (const float*)d_in[16];
    const float* fc2_b = (const float*)d_in[17];
    const float* lin_w = (const float*)d_in[18];
    const float* lin_g = (const float*)d_in[19];
    const float* lin_b = (const float*)d_in[20];

    const int N = in_sizes[0] / 22;
    const int E = in_sizes[1] / 2;
    const size_t nmp = (size_t)(N + 64) * NMAP;

    unsigned short* fbf   = (unsigned short*)d_ws;     // running feat
    unsigned short* h1bf  = fbf + nmp;
    unsigned short* aggbf = h1bf + nmp;
    unsigned short* x32   = aggbf + nmp;               // padded input feats
    unsigned short* wts   = x32 + (size_t)(N + 64) * 32;
    unsigned short* wend  = wts + 286720;

    int* rp   = (int*)wend;          // 2*(N+1)
    int* su   = rp + 2 * (N + 1);    // 2*E
    int* part = su + 2 * (size_t)E;  // scan partials (<=128)
    int* gcur = part + 256;          // 2*nbk (<=1024)
    int2* pairs = (int2*)aggbf;      // 16 MB; aggbf free until first seg_max

    const int nbk = (N + (1 << BKSH) - 1) >> BKSH;     // buckets per scale

    // ---- one-time converts ----
    cvt_feats_kernel<<<((N + 64) * 32 + 255) / 256, 256, 0, stream>>>(feats, x32, N);
    cvt_all_w<<<(286720 + 255) / 256, 256, 0, stream>>>(
        in_w1, in_wt, in_w2, fc1_w, fc2_w, lin_w, wts);

    // ---- one-time CSR build ----
    {
        const int n1 = N + 1;
        const int NB = (n1 + SCHUNK - 1) / SCHUNK;
        hipMemsetAsync(rp, 0, 2 * (size_t)n1 * sizeof(int), stream);
        hist2_kernel<<<(2 * E + 255) / 256, 256, 0, stream>>>(v, rp, E, N);
        scan1_kernel<<<2 * NB, 256, 0, stream>>>(rp, part, n1, NB);
        scan2_kernel<<<2, 256, 0, stream>>>(part, NB);
        scan3_kernel<<<2 * (NB - 1), 256, 0, stream>>>(rp, part, n1, NB);
        init_gcur<<<(2 * nbk + 255) / 256, 256, 0, stream>>>(rp, gcur, E, N, nbk);
        bucket_scatter<<<(2 * E + CH - 1) / CH, 256, 0, stream>>>(
            u, v, gcur, pairs, E, nbk);
        bucket_fill<<<2 * nbk, 256, 0, stream>>>(pairs, rp, su, E, N, nbk);
    }

    const int GB = (N + 31) / 32;
    const int GS = (N + 3) / 4;

    // ---- input stage + fc1[0] ----
    input_fused<<<GB, 256, 0, stream>>>(x32, wts,
        in_g1, in_b1, in_gt, in_bt, in_g2, in_b2,
        fc1_g, fc1_b, fbf, h1bf, N);

    // ---- agg blocks ----
    for (int k = 0; k < 4; ++k) {
        int is = k & 1;
        int has_next = (k < 3);
        seg_max_bf<<<GS, 256, 0, stream>>>(rp + (size_t)is * (N + 1),
            su + (size_t)is * E, (const unsigned*)h1bf, (unsigned*)aggbf, N);
        block_fused<<<GB, 256, 0, stream>>>(fbf, aggbf, wts, k,
            fc2_g + k * 128, fc2_b + k * 128,
            lin_g + k * 128, lin_b + k * 128,
            has_next ? fc1_g + (k + 1) * 128 : nullptr,
            has_next ? fc1_b + (k + 1) * 128 : nullptr,
            h1bf, (k == 3) ? (float*)d_out : nullptr, N, has_next);
    }
}

// Round 11
// 748.007 us; speedup vs baseline: 1.8171x; 1.0415x over previous
//
#include <hip/hip_runtime.h>

#define NMAP 128
#define EPSV 1e-5f
#define SCHUNK 2048     // elements per scan block (256 thr x 8)
#define HSTR 136        // LDS h-tile row stride in shorts (272 B)
#define BKSH 8          // 256 nodes per bucket
#define CH 8192         // edges per bucket_scatter workgroup

typedef __attribute__((ext_vector_type(8))) short bf16x8;   // 8 bf16 = 4 VGPRs
typedef __attribute__((ext_vector_type(4))) float f32x4;

__device__ __forceinline__ unsigned short f2bf(float f) {
    union { float f; unsigned u; } x; x.f = f;
    unsigned u = x.u;
    return (unsigned short)((u + 0x7fffu + ((u >> 16) & 1u)) >> 16);  // RNE
}
__device__ __forceinline__ float bf2f(unsigned short h) {
    union { unsigned u; float f; } x; x.u = ((unsigned)h) << 16;
    return x.f;
}

// M=32 tile: 4 waves; wave w -> cols [w*32,(w+1)*32), 2x2 fragments.
// row = mi*16 + lhi*4 + j (mi<2), col = w*32 + ni*16 + l15 (ni<2).
struct __align__(16) FSmem {
    unsigned short h[32 * HSTR];    // 8704 B  bf16 h-tile [32][136]
    unsigned short res[32 * HSTR];  // 8704 B  residual / h1o staging tile
    float red[2][4][36];            // 1152 B  per-wave GN partials
    float mv[32][2];                //  256 B  mean/rstd per row
};

// per-row mean/rstd over 128 cols -> s.mv
__device__ __forceinline__ void gn_stats(FSmem& s, const f32x4 acc[2][2],
                                         int w, int l15, int lhi, int tid)
{
    #pragma unroll
    for (int mi = 0; mi < 2; ++mi) {
        #pragma unroll
        for (int j = 0; j < 4; ++j) {
            float a0 = acc[mi][0][j], a1 = acc[mi][1][j];
            float s0 = a0 + a1, s1 = a0 * a0 + a1 * a1;
            #pragma unroll
            for (int m = 1; m < 16; m <<= 1) {
                s0 += __shfl_xor(s0, m);
                s1 += __shfl_xor(s1, m);
            }
            if (l15 == 0) {
                int row = mi * 16 + lhi * 4 + j;
                s.red[0][w][row] = s0;
                s.red[1][w][row] = s1;
            }
        }
    }
    __syncthreads();
    if (tid < 32) {
        float sm = 0.f, ss = 0.f;
        #pragma unroll
        for (int ww = 0; ww < 4; ++ww) { sm += s.red[0][ww][tid]; ss += s.red[1][ww][tid]; }
        float mean = sm * (1.f / 128.f);
        float var = ss * (1.f / 128.f) - mean * mean;
        s.mv[tid][0] = mean;
        s.mv[tid][1] = rsqrtf(var + EPSV);
    }
    __syncthreads();
}

// acc += h_lds @ WT[kwoff..]   (A from s.h)
__device__ __forceinline__ void gemm_lds(f32x4 acc[2][2], const FSmem& s,
    const unsigned short* __restrict__ WT, int K, int kwoff, int nks,
    int w, int l15, int lhi)
{
    #pragma unroll
    for (int ks = 0; ks < nks; ++ks) {
        bf16x8 af[2], bfr[2];
        #pragma unroll
        for (int mi = 0; mi < 2; ++mi)
            af[mi] = *(const bf16x8*)&s.h[(mi * 16 + l15) * HSTR + ks * 32 + lhi * 8];
        #pragma unroll
        for (int ni = 0; ni < 2; ++ni)
            bfr[ni] = *(const bf16x8*)&WT[(size_t)(w * 32 + ni * 16 + l15) * K + kwoff + ks * 32 + lhi * 8];
        #pragma unroll
        for (int mi = 0; mi < 2; ++mi)
            #pragma unroll
            for (int ni = 0; ni < 2; ++ni)
                acc[mi][ni] = __builtin_amdgcn_mfma_f32_16x16x32_bf16(
                    af[mi], bfr[ni], acc[mi][ni], 0, 0, 0);
    }
}

// acc += [Xf|Xa] @ WT (K=256), halves interleaved; wave 0 stashes Xf tile -> s.res
__device__ __forceinline__ void gemm_fc2(f32x4 acc[2][2], FSmem& s,
    const unsigned short* __restrict__ Xf, const unsigned short* __restrict__ Xa,
    const unsigned short* __restrict__ WT,
    int rowbase, int w, int l15, int lhi)
{
    #pragma unroll
    for (int ks = 0; ks < 4; ++ks) {
        bf16x8 afF[2], afA[2], bF[2], bA[2];
        #pragma unroll
        for (int mi = 0; mi < 2; ++mi) {
            size_t ro = (size_t)(rowbase + mi * 16 + l15) * 128 + ks * 32 + lhi * 8;
            afF[mi] = *(const bf16x8*)&Xf[ro];
            afA[mi] = *(const bf16x8*)&Xa[ro];
        }
        if (w == 0) {
            #pragma unroll
            for (int mi = 0; mi < 2; ++mi)
                *(bf16x8*)&s.res[(mi * 16 + l15) * HSTR + ks * 32 + lhi * 8] = afF[mi];
        }
        #pragma unroll
        for (int ni = 0; ni < 2; ++ni) {
            size_t co = (size_t)(w * 32 + ni * 16 + l15) * 256 + ks * 32 + lhi * 8;
            bF[ni] = *(const bf16x8*)&WT[co];
            bA[ni] = *(const bf16x8*)&WT[co + 128];
        }
        #pragma unroll
        for (int mi = 0; mi < 2; ++mi)
            #pragma unroll
            for (int ni = 0; ni < 2; ++ni) {
                acc[mi][ni] = __builtin_amdgcn_mfma_f32_16x16x32_bf16(
                    afF[mi], bF[ni], acc[mi][ni], 0, 0, 0);
                acc[mi][ni] = __builtin_amdgcn_mfma_f32_16x16x32_bf16(
                    afA[mi], bA[ni], acc[mi][ni], 0, 0, 0);
            }
    }
}

// GN + relu -> s.h
__device__ __forceinline__ void epi_lds(const f32x4 acc[2][2], FSmem& s,
    const float* __restrict__ g, const float* __restrict__ b, int w, int l15, int lhi)
{
    float gv[2], bv[2];
    #pragma unroll
    for (int ni = 0; ni < 2; ++ni) {
        int col = w * 32 + ni * 16 + l15;
        gv[ni] = g[col]; bv[ni] = b[col];
    }
    #pragma unroll
    for (int mi = 0; mi < 2; ++mi)
        #pragma unroll
        for (int j = 0; j < 4; ++j) {
            int row = mi * 16 + lhi * 4 + j;
            float mean = s.mv[row][0], rstd = s.mv[row][1];
            #pragma unroll
            for (int ni = 0; ni < 2; ++ni) {
                int col = w * 32 + ni * 16 + l15;
                float val = (acc[mi][ni][j] - mean) * rstd * gv[ni] + bv[ni];
                val = fmaxf(val, 0.f);
                s.h[row * HSTR + col] = f2bf(val);
            }
        }
}

// GN in-register (no relu)
__device__ __forceinline__ void norm_reg(f32x4 acc[2][2], const FSmem& s,
    const float* __restrict__ g, const float* __restrict__ b, int w, int l15, int lhi)
{
    float gv[2], bv[2];
    #pragma unroll
    for (int ni = 0; ni < 2; ++ni) {
        int col = w * 32 + ni * 16 + l15;
        gv[ni] = g[col]; bv[ni] = b[col];
    }
    #pragma unroll
    for (int mi = 0; mi < 2; ++mi)
        #pragma unroll
        for (int j = 0; j < 4; ++j) {
            int row = mi * 16 + lhi * 4 + j;
            float mean = s.mv[row][0], rstd = s.mv[row][1];
            #pragma unroll
            for (int ni = 0; ni < 2; ++ni)
                acc[mi][ni][j] = (acc[mi][ni][j] - mean) * rstd * gv[ni] + bv[ni];
        }
}

// vectorized tile writeout: LDS [32][HSTR] -> global [rowbase..][128]
__device__ __forceinline__ void vec_out(const unsigned short* __restrict__ t,
    unsigned short* __restrict__ dst, int rowbase, int nrows, int tid)
{
    #pragma unroll
    for (int it = 0; it < 2; ++it) {
        int c = tid * 2 + it;              // 0..511
        int row = c >> 4, col8 = (c & 15) * 8;
        if (rowbase + row < nrows)
            *(bf16x8*)&dst[(size_t)(rowbase + row) * NMAP + col8] =
                *(const bf16x8*)&t[row * HSTR + col8];
    }
}

// ---------------------------------------------------------------------------
// input stage + first fc1, all fused (M=32 tile)
__global__ __launch_bounds__(256) void input_fused(
    const unsigned short* __restrict__ X32,       // [N+64][32] bf16
    const unsigned short* __restrict__ wts,
    const float* __restrict__ g1, const float* __restrict__ b1,
    const float* __restrict__ gt, const float* __restrict__ bt,
    const float* __restrict__ g2, const float* __restrict__ b2,
    const float* __restrict__ g1n, const float* __restrict__ b1n,
    unsigned short* __restrict__ fbf, unsigned short* __restrict__ h1bf, int nrows)
{
    __shared__ FSmem s;
    const int tid = threadIdx.x;
    const int w = tid >> 6, l = tid & 63, l15 = l & 15, lhi = l >> 4;
    const int rowbase = blockIdx.x * 32;

    const unsigned short* w1T = wts;              // K=32
    const unsigned short* wtT = wts + 4096;       // K=32
    const unsigned short* w2T = wts + 8192;       // K=128
    const unsigned short* f1T = wts + 24576;      // fc1[0], K=128

    f32x4 accA[2][2] = {}, accT[2][2] = {};
    {
        bf16x8 af[2], b1f[2], btf[2];
        #pragma unroll
        for (int mi = 0; mi < 2; ++mi)
            af[mi] = *(const bf16x8*)&X32[(size_t)(rowbase + mi * 16 + l15) * 32 + lhi * 8];
        #pragma unroll
        for (int ni = 0; ni < 2; ++ni) {
            int col = w * 32 + ni * 16 + l15;
            b1f[ni] = *(const bf16x8*)&w1T[(size_t)col * 32 + lhi * 8];
            btf[ni] = *(const bf16x8*)&wtT[(size_t)col * 32 + lhi * 8];
        }
        #pragma unroll
        for (int mi = 0; mi < 2; ++mi)
            #pragma unroll
            for (int ni = 0; ni < 2; ++ni) {
                accA[mi][ni] = __builtin_amdgcn_mfma_f32_16x16x32_bf16(af[mi], b1f[ni], accA[mi][ni], 0, 0, 0);
                accT[mi][ni] = __builtin_amdgcn_mfma_f32_16x16x32_bf16(af[mi], btf[ni], accT[mi][ni], 0, 0, 0);
            }
    }

    gn_stats(s, accT, w, l15, lhi, tid);
    norm_reg(accT, s, gt, bt, w, l15, lhi);       // T = GN(X@wt), no relu
    gn_stats(s, accA, w, l15, lhi, tid);
    epi_lds(accA, s, g1, b1, w, l15, lhi);        // h1 -> s.h
    __syncthreads();

    // stage 1: feat = relu(GN(h1@w2) + T) -> s.h only
    f32x4 accB[2][2] = {};
    gemm_lds(accB, s, w2T, 128, 0, 4, w, l15, lhi);
    gn_stats(s, accB, w, l15, lhi, tid);
    {
        float gv[2], bv[2];
        #pragma unroll
        for (int ni = 0; ni < 2; ++ni) {
            int col = w * 32 + ni * 16 + l15;
            gv[ni] = g2[col]; bv[ni] = b2[col];
        }
        #pragma unroll
        for (int mi = 0; mi < 2; ++mi)
            #pragma unroll
            for (int j = 0; j < 4; ++j) {
                int rl = mi * 16 + lhi * 4 + j;
                float mean = s.mv[rl][0], rstd = s.mv[rl][1];
                #pragma unroll
                for (int ni = 0; ni < 2; ++ni) {
                    int col = w * 32 + ni * 16 + l15;
                    float val = (accB[mi][ni][j] - mean) * rstd * gv[ni] + bv[ni]
                              + accT[mi][ni][j];
                    s.h[rl * HSTR + col] = f2bf(fmaxf(val, 0.f));
                }
            }
    }
    __syncthreads();

    // stage 2: h1o = relu(GN(feat@fc1_0))
    f32x4 accC[2][2] = {};
    gemm_lds(accC, s, f1T, 128, 0, 4, w, l15, lhi);
    gn_stats(s, accC, w, l15, lhi, tid);           // ends with barrier
    vec_out(s.h, fbf, rowbase, nrows, tid);        // feat writeout (s.h intact)
    {
        float gv[2], bv[2];
        #pragma unroll
        for (int ni = 0; ni < 2; ++ni) {
            int col = w * 32 + ni * 16 + l15;
            gv[ni] = g1n[col]; bv[ni] = b1n[col];
        }
        #pragma unroll
        for (int mi = 0; mi < 2; ++mi)
            #pragma unroll
            for (int j = 0; j < 4; ++j) {
                int rl = mi * 16 + lhi * 4 + j;
                float mean = s.mv[rl][0], rstd = s.mv[rl][1];
                #pragma unroll
                for (int ni = 0; ni < 2; ++ni) {
                    int col = w * 32 + ni * 16 + l15;
                    float val = (accC[mi][ni][j] - mean) * rstd * gv[ni] + bv[ni];
                    s.res[rl * HSTR + col] = f2bf(fmaxf(val, 0.f));
                }
            }
    }
    __syncthreads();
    vec_out(s.res, h1bf, rowbase, nrows, tid);     // h1 writeout
}

// ---------------------------------------------------------------------------
// one agg block (minus seg_max), M=32 tile, LDS-stashed residual + vector IO
__global__ __launch_bounds__(256) void block_fused(
    unsigned short* __restrict__ fbf,
    const unsigned short* __restrict__ aggbf,
    const unsigned short* __restrict__ wts, int kblk,
    const float* __restrict__ g2, const float* __restrict__ b2,
    const float* __restrict__ gl, const float* __restrict__ bl,
    const float* __restrict__ g1n, const float* __restrict__ b1n,
    unsigned short* __restrict__ h1bf, float* __restrict__ outf,
    int nrows, int has_next)
{
    __shared__ FSmem s;
    const int tid = threadIdx.x;
    const int w = tid >> 6, l = tid & 63, l15 = l & 15, lhi = l >> 4;
    const int rowbase = blockIdx.x * 32;

    const unsigned short* fc2T = wts + 90112 + (size_t)kblk * 32768;   // K=256
    const unsigned short* linT = wts + 221184 + (size_t)kblk * 16384;  // K=128
    const unsigned short* f1T  = wts + 24576 + (size_t)(kblk + 1) * 16384;

    // stage 1: h = relu(GN([feat|agg]@fc2)); feat tile stashed -> s.res
    f32x4 acc2[2][2] = {};
    gemm_fc2(acc2, s, fbf, aggbf, fc2T, rowbase, w, l15, lhi);
    gn_stats(s, acc2, w, l15, lhi, tid);
    epi_lds(acc2, s, g2, b2, w, l15, lhi);
    __syncthreads();

    // stage 2: nf = relu(GN(h@lin) + feat)  (residual from s.res)
    f32x4 acc3[2][2] = {};
    gemm_lds(acc3, s, linT, 128, 0, 4, w, l15, lhi);
    gn_stats(s, acc3, w, l15, lhi, tid);
    {
        float gv[2], bv[2];
        #pragma unroll
        for (int ni = 0; ni < 2; ++ni) {
            int col = w * 32 + ni * 16 + l15;
            gv[ni] = gl[col]; bv[ni] = bl[col];
        }
        #pragma unroll
        for (int mi = 0; mi < 2; ++mi)
            #pragma unroll
            for (int j = 0; j < 4; ++j) {
                int rl = mi * 16 + lhi * 4 + j;
                int row = rowbase + rl;
                float mean = s.mv[rl][0], rstd = s.mv[rl][1];
                #pragma unroll
                for (int ni = 0; ni < 2; ++ni) {
                    int col = w * 32 + ni * 16 + l15;
                    float val = (acc3[mi][ni][j] - mean) * rstd * gv[ni] + bv[ni];
                    val += bf2f(s.res[rl * HSTR + col]);
                    val = fmaxf(val, 0.f);
                    s.h[rl * HSTR + col] = f2bf(val);
                    if (outf && row < nrows) outf[(size_t)row * NMAP + col] = val;
                }
            }
    }

    // stage 3: h1o = relu(GN(nf@fc1_next)); vectorized writeouts
    if (has_next) {
        __syncthreads();
        f32x4 acc4[2][2] = {};
        gemm_lds(acc4, s, f1T, 128, 0, 4, w, l15, lhi);
        gn_stats(s, acc4, w, l15, lhi, tid);       // ends with barrier
        vec_out(s.h, fbf, rowbase, nrows, tid);    // nf -> fbf (s.h intact)
        {
            float gv[2], bv[2];
            #pragma unroll
            for (int ni = 0; ni < 2; ++ni) {
                int col = w * 32 + ni * 16 + l15;
                gv[ni] = g1n[col]; bv[ni] = b1n[col];
            }
            #pragma unroll
            for (int mi = 0; mi < 2; ++mi)
                #pragma unroll
                for (int j = 0; j < 4; ++j) {
                    int rl = mi * 16 + lhi * 4 + j;
                    float mean = s.mv[rl][0], rstd = s.mv[rl][1];
                    #pragma unroll
                    for (int ni = 0; ni < 2; ++ni) {
                        int col = w * 32 + ni * 16 + l15;
                        float val = (acc4[mi][ni][j] - mean) * rstd * gv[ni] + bv[ni];
                        s.res[rl * HSTR + col] = f2bf(fmaxf(val, 0.f));
                    }
                }
        }
        __syncthreads();
        vec_out(s.res, h1bf, rowbase, nrows, tid); // h1o -> h1bf
    }
}

// ---------------------------------------------------------------------------
// all weight converts in one kernel.  wts layout (shorts):
//   w1T@0(4096) wtT@4096(4096) w2T@8192(16384) fc1T@24576(65536)
//   fc2T@90112(131072) linT@221184(65536)  total 286720
__global__ __launch_bounds__(256) void cvt_all_w(
    const float* __restrict__ in_w1, const float* __restrict__ in_wt,
    const float* __restrict__ in_w2, const float* __restrict__ fc1_w,
    const float* __restrict__ fc2_w, const float* __restrict__ lin_w,
    unsigned short* __restrict__ wts)
{
    int idx = blockIdx.x * 256 + threadIdx.x;
    if (idx >= 286720) return;
    const float* src; int off, K, Kreal;
    if (idx < 4096)        { src = in_w1; off = idx;          K = 32;  Kreal = 22; }
    else if (idx < 8192)   { src = in_wt; off = idx - 4096;   K = 32;  Kreal = 22; }
    else if (idx < 24576)  { src = in_w2; off = idx - 8192;   K = 128; Kreal = 128; }
    else if (idx < 90112)  { src = fc1_w; off = idx - 24576;  K = 128; Kreal = 128; }
    else if (idx < 221184) { src = fc2_w; off = idx - 90112;  K = 256; Kreal = 256; }
    else                   { src = lin_w; off = idx - 221184; K = 128; Kreal = 128; }
    int per = 128 * K;
    int m = off / per, rem = off - m * per;
    int c = rem / K, k = rem - c * K;
    float val = (k < Kreal) ? src[(size_t)m * per + (size_t)k * 128 + c] : 0.f;
    wts[idx] = f2bf(val);
}

// feats fp32 [N][22] -> bf16 [N+64][32] zero-padded
__global__ __launch_bounds__(256) void cvt_feats_kernel(
    const float* __restrict__ src, unsigned short* __restrict__ dst, int N)
{
    int idx = blockIdx.x * 256 + threadIdx.x;
    int n = idx >> 5, kk = idx & 31;
    if (n < N + 64) {
        float v = (n < N && kk < 22) ? src[(size_t)n * 22 + kk] : 0.f;
        dst[idx] = f2bf(v);
    }
}

// ---------------- CSR build: both scales fused per phase -------------------
__global__ __launch_bounds__(256) void hist2_kernel(
    const int* __restrict__ v, int* __restrict__ rp, int E, int N)
{
    int e = blockIdx.x * 256 + threadIdx.x;
    if (e < 2 * E) {
        int sc = e >= E;
        atomicAdd(&rp[sc * (N + 1) + v[e] + 1], 1);
    }
}

__global__ __launch_bounds__(256) void scan1_kernel(
    int* __restrict__ rp, int* __restrict__ part, int n1, int NB)
{
    __shared__ int wtot[4];
    const int sc = blockIdx.x / NB, chunk = blockIdx.x - sc * NB;
    int* data = rp + (size_t)sc * n1;
    const int tid = threadIdx.x;
    const int base = chunk * SCHUNK + tid * 8;
    int vv[8];
    #pragma unroll
    for (int i = 0; i < 8; ++i) {
        int idx = base + i;
        vv[i] = (idx < n1) ? data[idx] : 0;
    }
    #pragma unroll
    for (int i = 1; i < 8; ++i) vv[i] += vv[i - 1];
    int tsum = vv[7];
    const int lane = tid & 63, wid = tid >> 6;
    int scn = tsum;
    #pragma unroll
    for (int d = 1; d < 64; d <<= 1) {
        int t = __shfl_up(scn, d);
        if (lane >= d) scn += t;
    }
    if (lane == 63) wtot[wid] = scn;
    __syncthreads();
    int woff = 0;
    for (int w2 = 0; w2 < wid; ++w2) woff += wtot[w2];
    const int excl = scn - tsum + woff;
    #pragma unroll
    for (int i = 0; i < 8; ++i) {
        int idx = base + i;
        if (idx < n1) data[idx] = vv[i] + excl;
    }
    if (tid == 255) part[blockIdx.x] = excl + tsum;
}

__global__ __launch_bounds__(256) void scan2_kernel(int* part, int NB)
{
    __shared__ int wsum[4];
    int* data = part + blockIdx.x * NB;
    const int tid = threadIdx.x;
    const int lane = tid & 63, wid = tid >> 6;
    int carry = 0;
    for (int base = 0; base < NB; base += 256) {
        int i = base + tid;
        int val = (i < NB) ? data[i] : 0;
        #pragma unroll
        for (int d = 1; d < 64; d <<= 1) {
            int t = __shfl_up(val, d);
            if (lane >= d) val += t;
        }
        if (lane == 63) wsum[wid] = val;
        __syncthreads();
        int woff = 0;
        for (int w = 0; w < wid; ++w) woff += wsum[w];
        int total = wsum[0] + wsum[1] + wsum[2] + wsum[3];
        val += woff + carry;
        if (i < NB) data[i] = val;
        __syncthreads();
        carry += total;
    }
}

__global__ __launch_bounds__(256) void scan3_kernel(
    int* __restrict__ rp, const int* __restrict__ part, int n1, int NB)
{
    const int nbm1 = NB - 1;
    const int sc = blockIdx.x / nbm1, i = blockIdx.x - sc * nbm1;
    int* data = rp + (size_t)sc * n1;
    const int base = (i + 1) * SCHUNK + threadIdx.x * 8;
    const int off = part[sc * NB + i];
    #pragma unroll
    for (int q = 0; q < 8; ++q) {
        int idx = base + q;
        if (idx < n1) data[idx] += off;
    }
}

// gcur[bk] = sc*E + rp[sc][min(b*256, N)]
__global__ __launch_bounds__(256) void init_gcur(
    const int* __restrict__ rp, int* __restrict__ gcur, int E, int N, int nbk)
{
    int i = blockIdx.x * 256 + threadIdx.x;
    if (i < 2 * nbk) {
        int sc = i >= nbk;
        int b = i - sc * nbk;
        int nb0 = b << BKSH; if (nb0 > N) nb0 = N;
        gcur[i] = sc * E + rp[sc * (N + 1) + nb0];
    }
}

// pass 1: scatter (u,v) pairs into bucket regions (bucket = 256-node range)
__global__ __launch_bounds__(256) void bucket_scatter(
    const int* __restrict__ u, const int* __restrict__ v,
    int* __restrict__ gcur, int2* __restrict__ pairs, int E, int nbk)
{
    __shared__ int cnt[1024], base[1024];
    const int tid = threadIdx.x;
    const int tot = 2 * E;
    const int c0 = blockIdx.x * CH;
    const int nbk2 = 2 * nbk;
    for (int i = tid; i < nbk2; i += 256) cnt[i] = 0;
    __syncthreads();
    for (int i = 0; i < CH; i += 256) {
        int e = c0 + i + tid;
        if (e < tot) {
            int sc = e >= E;
            int vv = v[e];
            atomicAdd(&cnt[sc * nbk + (vv >> BKSH)], 1);
        }
    }
    __syncthreads();
    for (int i = tid; i < nbk2; i += 256) {
        int c = cnt[i];
        base[i] = c ? atomicAdd(&gcur[i], c) : 0;
        cnt[i] = 0;
    }
    __syncthreads();
    for (int i = 0; i < CH; i += 256) {
        int e = c0 + i + tid;
        if (e < tot) {
            int sc = e >= E;
            int uu = u[e], vv = v[e];
            int bk = sc * nbk + (vv >> BKSH);
            int off = atomicAdd(&cnt[bk], 1);
            pairs[(size_t)base[bk] + off] = make_int2(uu, vv);
        }
    }
}

// pass 2: per-bucket scatter into final CSR order (writes stay in ~10KB region)
__global__ __launch_bounds__(256) void bucket_fill(
    const int2* __restrict__ pairs, const int* __restrict__ rp,
    int* __restrict__ su, int E, int N, int nbk)
{
    __shared__ int curs[256];
    const int bk = blockIdx.x;
    const int sc = bk >= nbk;
    const int b = bk - sc * nbk;
    const int nb0 = b << BKSH;
    const int nb1 = min(nb0 + (1 << BKSH), N);
    const int nn = nb1 - nb0;
    const int* rps = rp + (size_t)sc * (N + 1);
    const int tid = threadIdx.x;
    const int rstart = rps[nb0], rend = rps[nb1];
    if (tid < nn) curs[tid] = rps[nb0 + tid];
    __syncthreads();
    int* sus = su + (size_t)sc * E;
    for (int idx = rstart + tid; idx < rend; idx += 256) {
        int2 pr = pairs[(size_t)sc * E + idx];
        int pos = atomicAdd(&curs[pr.y - nb0], 1);
        sus[pos] = pr.x;
    }
}

// agg[n][:] = max(0, max_{j in seg n} h1[su[j]][:])  -- bf16 bitwise u16 max
// 8-deep independent unroll: 8 gather rows in flight per wave
__global__ __launch_bounds__(256) void seg_max_bf(
    const int* __restrict__ rp, const int* __restrict__ su,
    const unsigned* __restrict__ h1, unsigned* __restrict__ agg, int N)
{
    int node = blockIdx.x * 4 + (threadIdx.x >> 6);
    int c = threadIdx.x & 63;
    if (node >= N) return;
    int s0 = rp[node], e0 = rp[node + 1];
    unsigned lo[8] = {0,0,0,0,0,0,0,0}, hi[8] = {0,0,0,0,0,0,0,0};
    int j = s0;
    for (; j + 7 < e0; j += 8) {
        unsigned x[8];
        #pragma unroll
        for (int q = 0; q < 8; ++q) x[q] = h1[(size_t)su[j + q] * 64 + c];
        #pragma unroll
        for (int q = 0; q < 8; ++q) {
            lo[q] = max(lo[q], x[q] & 0xffffu);
            hi[q] = max(hi[q], x[q] >> 16);
        }
    }
    for (; j < e0; ++j) {
        unsigned x0 = h1[(size_t)su[j] * 64 + c];
        lo[0] = max(lo[0], x0 & 0xffffu); hi[0] = max(hi[0], x0 >> 16);
    }
    #pragma unroll
    for (int q = 4; q > 0; q >>= 1)
        #pragma unroll
        for (int r = 0; r < q; ++r) {
            lo[r] = max(lo[r], lo[r + q]);
            hi[r] = max(hi[r], hi[r + q]);
        }
    agg[(size_t)node * 64 + c] = lo[0] | (hi[0] << 16);
}

// ---------------------------------------------------------------------------
extern "C" void kernel_launch(void* const* d_in, const int* in_sizes, int n_in,
                              void* d_out, int out_size, void* d_ws, size_t ws_size,
                              hipStream_t stream)
{
    const float* feats = (const float*)d_in[0];
    const int*   u     = (const int*)d_in[1];
    const int*   v     = (const int*)d_in[2];
    const float* in_w1 = (const float*)d_in[3];
    const float* in_g1 = (const float*)d_in[4];
    const float* in_b1 = (const float*)d_in[5];
    const float* in_w2 = (const float*)d_in[6];
    const float* in_g2 = (const float*)d_in[7];
    const float* in_b2 = (const float*)d_in[8];
    const float* in_wt = (const float*)d_in[9];
    const float* in_gt = (const float*)d_in[10];
    const float* in_bt = (const float*)d_in[11];
    const float* fc1_w = (const float*)d_in[12];
    const float* fc1_g = (const float*)d_in[13];
    const float* fc1_b = (const float*)d_in[14];
    const float* fc2_w = (const float*)d_in[15];
    const float* fc2_g = (const float*)d_in[16];
    const float* fc2_b = (const float*)d_in[17];
    const float* lin_w = (const float*)d_in[18];
    const float* lin_g = (const float*)d_in[19];
    const float* lin_b = (const float*)d_in[20];

    const int N = in_sizes[0] / 22;
    const int E = in_sizes[1] / 2;
    const size_t nmp = (size_t)(N + 64) * NMAP;

    unsigned short* fbf   = (unsigned short*)d_ws;     // running feat
    unsigned short* h1bf  = fbf + nmp;
    unsigned short* aggbf = h1bf + nmp;
    unsigned short* x32   = aggbf + nmp;               // padded input feats
    unsigned short* wts   = x32 + (size_t)(N + 64) * 32;
    unsigned short* wend  = wts + 286720;

    int* rp   = (int*)wend;          // 2*(N+1)
    int* su   = rp + 2 * (N + 1);    // 2*E
    int* part = su + 2 * (size_t)E;  // scan partials (<=128)
    int* gcur = part + 256;          // 2*nbk (<=1024)
    int2* pairs = (int2*)aggbf;      // 16 MB; aggbf free until first seg_max

    const int nbk = (N + (1 << BKSH) - 1) >> BKSH;     // buckets per scale

    // ---- one-time converts ----
    cvt_feats_kernel<<<((N + 64) * 32 + 255) / 256, 256, 0, stream>>>(feats, x32, N);
    cvt_all_w<<<(286720 + 255) / 256, 256, 0, stream>>>(
        in_w1, in_wt, in_w2, fc1_w, fc2_w, lin_w, wts);

    // ---- one-time CSR build ----
    {
        const int n1 = N + 1;
        const int NB = (n1 + SCHUNK - 1) / SCHUNK;
        hipMemsetAsync(rp, 0, 2 * (size_t)n1 * sizeof(int), stream);
        hist2_kernel<<<(2 * E + 255) / 256, 256, 0, stream>>>(v, rp, E, N);
        scan1_kernel<<<2 * NB, 256, 0, stream>>>(rp, part, n1, NB);
        scan2_kernel<<<2, 256, 0, stream>>>(part, NB);
        scan3_kernel<<<2 * (NB - 1), 256, 0, stream>>>(rp, part, n1, NB);
        init_gcur<<<(2 * nbk + 255) / 256, 256, 0, stream>>>(rp, gcur, E, N, nbk);
        bucket_scatter<<<(2 * E + CH - 1) / CH, 256, 0, stream>>>(
            u, v, gcur, pairs, E, nbk);
        bucket_fill<<<2 * nbk, 256, 0, stream>>>(pairs, rp, su, E, N, nbk);
    }

    const int GB = (N + 31) / 32;
    const int GS = (N + 3) / 4;

    // ---- input stage + fc1[0] ----
    input_fused<<<GB, 256, 0, stream>>>(x32, wts,
        in_g1, in_b1, in_gt, in_bt, in_g2, in_b2,
        fc1_g, fc1_b, fbf, h1bf, N);

    // ---- agg blocks ----
    for (int k = 0; k < 4; ++k) {
        int is = k & 1;
        int has_next = (k < 3);
        seg_max_bf<<<GS, 256, 0, stream>>>(rp + (size_t)is * (N + 1),
            su + (size_t)is * E, (const unsigned*)h1bf, (unsigned*)aggbf, N);
        block_fused<<<GB, 256, 0, stream>>>(fbf, aggbf, wts, k,
            fc2_g + k * 128, fc2_b + k * 128,
            lin_g + k * 128, lin_b + k * 128,
            has_next ? fc1_g + (k + 1) * 128 : nullptr,
            has_next ? fc1_b + (k + 1) * 128 : nullptr,
            h1bf, (k == 3) ? (float*)d_out : nullptr, N, has_next);
    }
}

// Round 12
// 730.707 us; speedup vs baseline: 1.8601x; 1.0237x over previous
//
#include <hip/hip_runtime.h>

#define NMAP 128
#define EPSV 1e-5f
#define SCHUNK 2048     // elements per scan block (256 thr x 8)
#define HSTR 136        // LDS h-tile row stride in shorts (272 B)
#define BKSH 8          // 256 nodes per bucket
#define CH 8192         // edges per bucket_scatter workgroup

typedef __attribute__((ext_vector_type(8))) short bf16x8;   // 8 bf16 = 4 VGPRs
typedef __attribute__((ext_vector_type(4))) float f32x4;

__device__ __forceinline__ unsigned short f2bf(float f) {
    union { float f; unsigned u; } x; x.f = f;
    unsigned u = x.u;
    return (unsigned short)((u + 0x7fffu + ((u >> 16) & 1u)) >> 16);  // RNE
}
__device__ __forceinline__ float bf2f(unsigned short h) {
    union { unsigned u; float f; } x; x.u = ((unsigned)h) << 16;
    return x.f;
}
// two f32 -> packed bf16 pair (RNE, same rounding as f2bf), 1 VALU op
__device__ __forceinline__ unsigned cvt_pk_bf16(float lo, float hi) {
    unsigned r;
    asm("v_cvt_pk_bf16_f32 %0, %1, %2" : "=v"(r) : "v"(lo), "v"(hi));
    return r;
}

// M=32 tile: 4 waves; wave w -> cols [w*32,(w+1)*32), 2x2 fragments.
// row = mi*16 + lhi*4 + j (mi<2), col = w*32 + ni*16 + l15 (ni<2).
struct __align__(16) FSmem {
    unsigned short h[32 * HSTR];    // 8704 B  bf16 h-tile [32][136]
    unsigned short res[32 * HSTR];  // 8704 B  residual / h1o staging tile
    float2 red[4][4][34];           // 4352 B  GN partials [w][cg][row], (sum,ss)
    float mv[32][2];                //  256 B  mean/rstd per row
};

// per-row mean/rstd over 128 cols -> s.mv  (2 shfl stages + packed LDS finish)
__device__ __forceinline__ void gn_stats(FSmem& s, const f32x4 acc[2][2],
                                         int w, int l15, int lhi, int tid)
{
    const int cg = l15 >> 2;
    #pragma unroll
    for (int mi = 0; mi < 2; ++mi) {
        #pragma unroll
        for (int j = 0; j < 4; ++j) {
            float a0 = acc[mi][0][j], a1 = acc[mi][1][j];
            float s0 = a0 + a1, s1 = a0 * a0 + a1 * a1;
            s0 += __shfl_xor(s0, 1); s1 += __shfl_xor(s1, 1);
            s0 += __shfl_xor(s0, 2); s1 += __shfl_xor(s1, 2);
            if ((l15 & 3) == 0) {
                int row = mi * 16 + lhi * 4 + j;
                s.red[w][cg][row] = make_float2(s0, s1);
            }
        }
    }
    __syncthreads();
    if (tid < 32) {
        float sm = 0.f, ss = 0.f;
        #pragma unroll
        for (int ww = 0; ww < 4; ++ww)
            #pragma unroll
            for (int cgg = 0; cgg < 4; ++cgg) {
                float2 p = s.red[ww][cgg][tid];
                sm += p.x; ss += p.y;
            }
        float mean = sm * (1.f / 128.f);
        float var = ss * (1.f / 128.f) - mean * mean;
        s.mv[tid][0] = mean;
        s.mv[tid][1] = rsqrtf(var + EPSV);
    }
    __syncthreads();
}

// acc += h_lds @ WT[kwoff..]   (A from s.h)
__device__ __forceinline__ void gemm_lds(f32x4 acc[2][2], const FSmem& s,
    const unsigned short* __restrict__ WT, int K, int kwoff, int nks,
    int w, int l15, int lhi)
{
    #pragma unroll
    for (int ks = 0; ks < nks; ++ks) {
        bf16x8 af[2], bfr[2];
        #pragma unroll
        for (int mi = 0; mi < 2; ++mi)
            af[mi] = *(const bf16x8*)&s.h[(mi * 16 + l15) * HSTR + ks * 32 + lhi * 8];
        #pragma unroll
        for (int ni = 0; ni < 2; ++ni)
            bfr[ni] = *(const bf16x8*)&WT[(size_t)(w * 32 + ni * 16 + l15) * K + kwoff + ks * 32 + lhi * 8];
        #pragma unroll
        for (int mi = 0; mi < 2; ++mi)
            #pragma unroll
            for (int ni = 0; ni < 2; ++ni)
                acc[mi][ni] = __builtin_amdgcn_mfma_f32_16x16x32_bf16(
                    af[mi], bfr[ni], acc[mi][ni], 0, 0, 0);
    }
}

// acc += [Xf|Xa] @ WT (K=256), halves interleaved; wave 0 stashes Xf tile -> s.res
__device__ __forceinline__ void gemm_fc2(f32x4 acc[2][2], FSmem& s,
    const unsigned short* __restrict__ Xf, const unsigned short* __restrict__ Xa,
    const unsigned short* __restrict__ WT,
    int rowbase, int w, int l15, int lhi)
{
    #pragma unroll
    for (int ks = 0; ks < 4; ++ks) {
        bf16x8 afF[2], afA[2], bF[2], bA[2];
        #pragma unroll
        for (int mi = 0; mi < 2; ++mi) {
            size_t ro = (size_t)(rowbase + mi * 16 + l15) * 128 + ks * 32 + lhi * 8;
            afF[mi] = *(const bf16x8*)&Xf[ro];
            afA[mi] = *(const bf16x8*)&Xa[ro];
        }
        if (w == 0) {
            #pragma unroll
            for (int mi = 0; mi < 2; ++mi)
                *(bf16x8*)&s.res[(mi * 16 + l15) * HSTR + ks * 32 + lhi * 8] = afF[mi];
        }
        #pragma unroll
        for (int ni = 0; ni < 2; ++ni) {
            size_t co = (size_t)(w * 32 + ni * 16 + l15) * 256 + ks * 32 + lhi * 8;
            bF[ni] = *(const bf16x8*)&WT[co];
            bA[ni] = *(const bf16x8*)&WT[co + 128];
        }
        #pragma unroll
        for (int mi = 0; mi < 2; ++mi)
            #pragma unroll
            for (int ni = 0; ni < 2; ++ni) {
                acc[mi][ni] = __builtin_amdgcn_mfma_f32_16x16x32_bf16(
                    afF[mi], bF[ni], acc[mi][ni], 0, 0, 0);
                acc[mi][ni] = __builtin_amdgcn_mfma_f32_16x16x32_bf16(
                    afA[mi], bA[ni], acc[mi][ni], 0, 0, 0);
            }
    }
}

// GN + relu -> s.h  (cvt_pk pairs the two ni columns)
__device__ __forceinline__ void epi_lds(const f32x4 acc[2][2], FSmem& s,
    const float* __restrict__ g, const float* __restrict__ b, int w, int l15, int lhi)
{
    float gv[2], bv[2];
    #pragma unroll
    for (int ni = 0; ni < 2; ++ni) {
        int col = w * 32 + ni * 16 + l15;
        gv[ni] = g[col]; bv[ni] = b[col];
    }
    #pragma unroll
    for (int mi = 0; mi < 2; ++mi)
        #pragma unroll
        for (int j = 0; j < 4; ++j) {
            int row = mi * 16 + lhi * 4 + j;
            float mean = s.mv[row][0], rstd = s.mv[row][1];
            float v0 = fmaxf((acc[mi][0][j] - mean) * rstd * gv[0] + bv[0], 0.f);
            float v1 = fmaxf((acc[mi][1][j] - mean) * rstd * gv[1] + bv[1], 0.f);
            unsigned pk = cvt_pk_bf16(v0, v1);
            int c0 = w * 32 + l15;
            s.h[row * HSTR + c0]      = (unsigned short)pk;
            s.h[row * HSTR + c0 + 16] = (unsigned short)(pk >> 16);
        }
}

// GN in-register (no relu)
__device__ __forceinline__ void norm_reg(f32x4 acc[2][2], const FSmem& s,
    const float* __restrict__ g, const float* __restrict__ b, int w, int l15, int lhi)
{
    float gv[2], bv[2];
    #pragma unroll
    for (int ni = 0; ni < 2; ++ni) {
        int col = w * 32 + ni * 16 + l15;
        gv[ni] = g[col]; bv[ni] = b[col];
    }
    #pragma unroll
    for (int mi = 0; mi < 2; ++mi)
        #pragma unroll
        for (int j = 0; j < 4; ++j) {
            int row = mi * 16 + lhi * 4 + j;
            float mean = s.mv[row][0], rstd = s.mv[row][1];
            #pragma unroll
            for (int ni = 0; ni < 2; ++ni)
                acc[mi][ni][j] = (acc[mi][ni][j] - mean) * rstd * gv[ni] + bv[ni];
        }
}

// vectorized tile writeout: LDS [32][HSTR] -> global [rowbase..][128]
__device__ __forceinline__ void vec_out(const unsigned short* __restrict__ t,
    unsigned short* __restrict__ dst, int rowbase, int nrows, int tid)
{
    #pragma unroll
    for (int it = 0; it < 2; ++it) {
        int c = tid * 2 + it;              // 0..511
        int row = c >> 4, col8 = (c & 15) * 8;
        if (rowbase + row < nrows)
            *(bf16x8*)&dst[(size_t)(rowbase + row) * NMAP + col8] =
                *(const bf16x8*)&t[row * HSTR + col8];
    }
}

// ---------------------------------------------------------------------------
// input stage + first fc1, all fused (M=32 tile)
__global__ __launch_bounds__(256) void input_fused(
    const unsigned short* __restrict__ X32,       // [N+64][32] bf16
    const unsigned short* __restrict__ wts,
    const float* __restrict__ g1, const float* __restrict__ b1,
    const float* __restrict__ gt, const float* __restrict__ bt,
    const float* __restrict__ g2, const float* __restrict__ b2,
    const float* __restrict__ g1n, const float* __restrict__ b1n,
    unsigned short* __restrict__ fbf, unsigned short* __restrict__ h1bf, int nrows)
{
    __shared__ FSmem s;
    const int tid = threadIdx.x;
    const int w = tid >> 6, l = tid & 63, l15 = l & 15, lhi = l >> 4;
    const int rowbase = blockIdx.x * 32;

    const unsigned short* w1T = wts;              // K=32
    const unsigned short* wtT = wts + 4096;       // K=32
    const unsigned short* w2T = wts + 8192;       // K=128
    const unsigned short* f1T = wts + 24576;      // fc1[0], K=128

    f32x4 accA[2][2] = {}, accT[2][2] = {};
    {
        bf16x8 af[2], b1f[2], btf[2];
        #pragma unroll
        for (int mi = 0; mi < 2; ++mi)
            af[mi] = *(const bf16x8*)&X32[(size_t)(rowbase + mi * 16 + l15) * 32 + lhi * 8];
        #pragma unroll
        for (int ni = 0; ni < 2; ++ni) {
            int col = w * 32 + ni * 16 + l15;
            b1f[ni] = *(const bf16x8*)&w1T[(size_t)col * 32 + lhi * 8];
            btf[ni] = *(const bf16x8*)&wtT[(size_t)col * 32 + lhi * 8];
        }
        #pragma unroll
        for (int mi = 0; mi < 2; ++mi)
            #pragma unroll
            for (int ni = 0; ni < 2; ++ni) {
                accA[mi][ni] = __builtin_amdgcn_mfma_f32_16x16x32_bf16(af[mi], b1f[ni], accA[mi][ni], 0, 0, 0);
                accT[mi][ni] = __builtin_amdgcn_mfma_f32_16x16x32_bf16(af[mi], btf[ni], accT[mi][ni], 0, 0, 0);
            }
    }

    gn_stats(s, accT, w, l15, lhi, tid);
    norm_reg(accT, s, gt, bt, w, l15, lhi);       // T = GN(X@wt), no relu
    gn_stats(s, accA, w, l15, lhi, tid);
    epi_lds(accA, s, g1, b1, w, l15, lhi);        // h1 -> s.h
    __syncthreads();

    // stage 1: feat = relu(GN(h1@w2) + T) -> s.h only
    f32x4 accB[2][2] = {};
    gemm_lds(accB, s, w2T, 128, 0, 4, w, l15, lhi);
    gn_stats(s, accB, w, l15, lhi, tid);
    {
        float gv[2], bv[2];
        #pragma unroll
        for (int ni = 0; ni < 2; ++ni) {
            int col = w * 32 + ni * 16 + l15;
            gv[ni] = g2[col]; bv[ni] = b2[col];
        }
        #pragma unroll
        for (int mi = 0; mi < 2; ++mi)
            #pragma unroll
            for (int j = 0; j < 4; ++j) {
                int rl = mi * 16 + lhi * 4 + j;
                float mean = s.mv[rl][0], rstd = s.mv[rl][1];
                float v0 = fmaxf((accB[mi][0][j] - mean) * rstd * gv[0] + bv[0]
                                 + accT[mi][0][j], 0.f);
                float v1 = fmaxf((accB[mi][1][j] - mean) * rstd * gv[1] + bv[1]
                                 + accT[mi][1][j], 0.f);
                unsigned pk = cvt_pk_bf16(v0, v1);
                int c0 = w * 32 + l15;
                s.h[rl * HSTR + c0]      = (unsigned short)pk;
                s.h[rl * HSTR + c0 + 16] = (unsigned short)(pk >> 16);
            }
    }
    __syncthreads();

    // stage 2: h1o = relu(GN(feat@fc1_0))
    f32x4 accC[2][2] = {};
    gemm_lds(accC, s, f1T, 128, 0, 4, w, l15, lhi);
    gn_stats(s, accC, w, l15, lhi, tid);           // ends with barrier
    vec_out(s.h, fbf, rowbase, nrows, tid);        // feat writeout (s.h intact)
    {
        float gv[2], bv[2];
        #pragma unroll
        for (int ni = 0; ni < 2; ++ni) {
            int col = w * 32 + ni * 16 + l15;
            gv[ni] = g1n[col]; bv[ni] = b1n[col];
        }
        #pragma unroll
        for (int mi = 0; mi < 2; ++mi)
            #pragma unroll
            for (int j = 0; j < 4; ++j) {
                int rl = mi * 16 + lhi * 4 + j;
                float mean = s.mv[rl][0], rstd = s.mv[rl][1];
                float v0 = fmaxf((accC[mi][0][j] - mean) * rstd * gv[0] + bv[0], 0.f);
                float v1 = fmaxf((accC[mi][1][j] - mean) * rstd * gv[1] + bv[1], 0.f);
                unsigned pk = cvt_pk_bf16(v0, v1);
                int c0 = w * 32 + l15;
                s.res[rl * HSTR + c0]      = (unsigned short)pk;
                s.res[rl * HSTR + c0 + 16] = (unsigned short)(pk >> 16);
            }
    }
    __syncthreads();
    vec_out(s.res, h1bf, rowbase, nrows, tid);     // h1 writeout
}

// ---------------------------------------------------------------------------
// one agg block (minus seg_max), M=32 tile, LDS-stashed residual + vector IO
__global__ __launch_bounds__(256) void block_fused(
    unsigned short* __restrict__ fbf,
    const unsigned short* __restrict__ aggbf,
    const unsigned short* __restrict__ wts, int kblk,
    const float* __restrict__ g2, const float* __restrict__ b2,
    const float* __restrict__ gl, const float* __restrict__ bl,
    const float* __restrict__ g1n, const float* __restrict__ b1n,
    unsigned short* __restrict__ h1bf, float* __restrict__ outf,
    int nrows, int has_next)
{
    __shared__ FSmem s;
    const int tid = threadIdx.x;
    const int w = tid >> 6, l = tid & 63, l15 = l & 15, lhi = l >> 4;
    const int rowbase = blockIdx.x * 32;

    const unsigned short* fc2T = wts + 90112 + (size_t)kblk * 32768;   // K=256
    const unsigned short* linT = wts + 221184 + (size_t)kblk * 16384;  // K=128
    const unsigned short* f1T  = wts + 24576 + (size_t)(kblk + 1) * 16384;

    // stage 1: h = relu(GN([feat|agg]@fc2)); feat tile stashed -> s.res
    f32x4 acc2[2][2] = {};
    gemm_fc2(acc2, s, fbf, aggbf, fc2T, rowbase, w, l15, lhi);
    gn_stats(s, acc2, w, l15, lhi, tid);
    epi_lds(acc2, s, g2, b2, w, l15, lhi);
    __syncthreads();

    // stage 2: nf = relu(GN(h@lin) + feat)  (residual from s.res)
    f32x4 acc3[2][2] = {};
    gemm_lds(acc3, s, linT, 128, 0, 4, w, l15, lhi);
    gn_stats(s, acc3, w, l15, lhi, tid);
    {
        float gv[2], bv[2];
        #pragma unroll
        for (int ni = 0; ni < 2; ++ni) {
            int col = w * 32 + ni * 16 + l15;
            gv[ni] = gl[col]; bv[ni] = bl[col];
        }
        #pragma unroll
        for (int mi = 0; mi < 2; ++mi)
            #pragma unroll
            for (int j = 0; j < 4; ++j) {
                int rl = mi * 16 + lhi * 4 + j;
                int row = rowbase + rl;
                float mean = s.mv[rl][0], rstd = s.mv[rl][1];
                int c0 = w * 32 + l15;
                float v0 = (acc3[mi][0][j] - mean) * rstd * gv[0] + bv[0]
                         + bf2f(s.res[rl * HSTR + c0]);
                float v1 = (acc3[mi][1][j] - mean) * rstd * gv[1] + bv[1]
                         + bf2f(s.res[rl * HSTR + c0 + 16]);
                v0 = fmaxf(v0, 0.f); v1 = fmaxf(v1, 0.f);
                unsigned pk = cvt_pk_bf16(v0, v1);
                s.h[rl * HSTR + c0]      = (unsigned short)pk;
                s.h[rl * HSTR + c0 + 16] = (unsigned short)(pk >> 16);
                if (outf && row < nrows) {
                    outf[(size_t)row * NMAP + c0]      = v0;
                    outf[(size_t)row * NMAP + c0 + 16] = v1;
                }
            }
    }

    // stage 3: h1o = relu(GN(nf@fc1_next)); vectorized writeouts
    if (has_next) {
        __syncthreads();
        f32x4 acc4[2][2] = {};
        gemm_lds(acc4, s, f1T, 128, 0, 4, w, l15, lhi);
        gn_stats(s, acc4, w, l15, lhi, tid);       // ends with barrier
        vec_out(s.h, fbf, rowbase, nrows, tid);    // nf -> fbf (s.h intact)
        {
            float gv[2], bv[2];
            #pragma unroll
            for (int ni = 0; ni < 2; ++ni) {
                int col = w * 32 + ni * 16 + l15;
                gv[ni] = g1n[col]; bv[ni] = b1n[col];
            }
            #pragma unroll
            for (int mi = 0; mi < 2; ++mi)
                #pragma unroll
                for (int j = 0; j < 4; ++j) {
                    int rl = mi * 16 + lhi * 4 + j;
                    float mean = s.mv[rl][0], rstd = s.mv[rl][1];
                    float v0 = fmaxf((acc4[mi][0][j] - mean) * rstd * gv[0] + bv[0], 0.f);
                    float v1 = fmaxf((acc4[mi][1][j] - mean) * rstd * gv[1] + bv[1], 0.f);
                    unsigned pk = cvt_pk_bf16(v0, v1);
                    int c0 = w * 32 + l15;
                    s.res[rl * HSTR + c0]      = (unsigned short)pk;
                    s.res[rl * HSTR + c0 + 16] = (unsigned short)(pk >> 16);
                }
        }
        __syncthreads();
        vec_out(s.res, h1bf, rowbase, nrows, tid); // h1o -> h1bf
    }
}

// ---------------------------------------------------------------------------
// all weight converts in one kernel.  wts layout (shorts):
//   w1T@0(4096) wtT@4096(4096) w2T@8192(16384) fc1T@24576(65536)
//   fc2T@90112(131072) linT@221184(65536)  total 286720
__global__ __launch_bounds__(256) void cvt_all_w(
    const float* __restrict__ in_w1, const float* __restrict__ in_wt,
    const float* __restrict__ in_w2, const float* __restrict__ fc1_w,
    const float* __restrict__ fc2_w, const float* __restrict__ lin_w,
    unsigned short* __restrict__ wts)
{
    int idx = blockIdx.x * 256 + threadIdx.x;
    if (idx >= 286720) return;
    const float* src; int off, K, Kreal;
    if (idx < 4096)        { src = in_w1; off = idx;          K = 32;  Kreal = 22; }
    else if (idx < 8192)   { src = in_wt; off = idx - 4096;   K = 32;  Kreal = 22; }
    else if (idx < 24576)  { src = in_w2; off = idx - 8192;   K = 128; Kreal = 128; }
    else if (idx < 90112)  { src = fc1_w; off = idx - 24576;  K = 128; Kreal = 128; }
    else if (idx < 221184) { src = fc2_w; off = idx - 90112;  K = 256; Kreal = 256; }
    else                   { src = lin_w; off = idx - 221184; K = 128; Kreal = 128; }
    int per = 128 * K;
    int m = off / per, rem = off - m * per;
    int c = rem / K, k = rem - c * K;
    float val = (k < Kreal) ? src[(size_t)m * per + (size_t)k * 128 + c] : 0.f;
    wts[idx] = f2bf(val);
}

// feats fp32 [N][22] -> bf16 [N+64][32] zero-padded
__global__ __launch_bounds__(256) void cvt_feats_kernel(
    const float* __restrict__ src, unsigned short* __restrict__ dst, int N)
{
    int idx = blockIdx.x * 256 + threadIdx.x;
    int n = idx >> 5, kk = idx & 31;
    if (n < N + 64) {
        float v = (n < N && kk < 22) ? src[(size_t)n * 22 + kk] : 0.f;
        dst[idx] = f2bf(v);
    }
}

// ---------------- CSR build: both scales fused per phase -------------------
__global__ __launch_bounds__(256) void hist2_kernel(
    const int* __restrict__ v, int* __restrict__ rp, int E, int N)
{
    int e = blockIdx.x * 256 + threadIdx.x;
    if (e < 2 * E) {
        int sc = e >= E;
        atomicAdd(&rp[sc * (N + 1) + v[e] + 1], 1);
    }
}

__global__ __launch_bounds__(256) void scan1_kernel(
    int* __restrict__ rp, int* __restrict__ part, int n1, int NB)
{
    __shared__ int wtot[4];
    const int sc = blockIdx.x / NB, chunk = blockIdx.x - sc * NB;
    int* data = rp + (size_t)sc * n1;
    const int tid = threadIdx.x;
    const int base = chunk * SCHUNK + tid * 8;
    int vv[8];
    #pragma unroll
    for (int i = 0; i < 8; ++i) {
        int idx = base + i;
        vv[i] = (idx < n1) ? data[idx] : 0;
    }
    #pragma unroll
    for (int i = 1; i < 8; ++i) vv[i] += vv[i - 1];
    int tsum = vv[7];
    const int lane = tid & 63, wid = tid >> 6;
    int scn = tsum;
    #pragma unroll
    for (int d = 1; d < 64; d <<= 1) {
        int t = __shfl_up(scn, d);
        if (lane >= d) scn += t;
    }
    if (lane == 63) wtot[wid] = scn;
    __syncthreads();
    int woff = 0;
    for (int w2 = 0; w2 < wid; ++w2) woff += wtot[w2];
    const int excl = scn - tsum + woff;
    #pragma unroll
    for (int i = 0; i < 8; ++i) {
        int idx = base + i;
        if (idx < n1) data[idx] = vv[i] + excl;
    }
    if (tid == 255) part[blockIdx.x] = excl + tsum;
}

__global__ __launch_bounds__(256) void scan2_kernel(int* part, int NB)
{
    __shared__ int wsum[4];
    int* data = part + blockIdx.x * NB;
    const int tid = threadIdx.x;
    const int lane = tid & 63, wid = tid >> 6;
    int carry = 0;
    for (int base = 0; base < NB; base += 256) {
        int i = base + tid;
        int val = (i < NB) ? data[i] : 0;
        #pragma unroll
        for (int d = 1; d < 64; d <<= 1) {
            int t = __shfl_up(val, d);
            if (lane >= d) val += t;
        }
        if (lane == 63) wsum[wid] = val;
        __syncthreads();
        int woff = 0;
        for (int w = 0; w < wid; ++w) woff += wsum[w];
        int total = wsum[0] + wsum[1] + wsum[2] + wsum[3];
        val += woff + carry;
        if (i < NB) data[i] = val;
        __syncthreads();
        carry += total;
    }
}

__global__ __launch_bounds__(256) void scan3_kernel(
    int* __restrict__ rp, const int* __restrict__ part, int n1, int NB)
{
    const int nbm1 = NB - 1;
    const int sc = blockIdx.x / nbm1, i = blockIdx.x - sc * nbm1;
    int* data = rp + (size_t)sc * n1;
    const int base = (i + 1) * SCHUNK + threadIdx.x * 8;
    const int off = part[sc * NB + i];
    #pragma unroll
    for (int q = 0; q < 8; ++q) {
        int idx = base + q;
        if (idx < n1) data[idx] += off;
    }
}

// gcur[bk] = sc*E + rp[sc][min(b*256, N)]
__global__ __launch_bounds__(256) void init_gcur(
    const int* __restrict__ rp, int* __restrict__ gcur, int E, int N, int nbk)
{
    int i = blockIdx.x * 256 + threadIdx.x;
    if (i < 2 * nbk) {
        int sc = i >= nbk;
        int b = i - sc * nbk;
        int nb0 = b << BKSH; if (nb0 > N) nb0 = N;
        gcur[i] = sc * E + rp[sc * (N + 1) + nb0];
    }
}

// pass 1: scatter (u,v) pairs into bucket regions (bucket = 256-node range)
__global__ __launch_bounds__(256) void bucket_scatter(
    const int* __restrict__ u, const int* __restrict__ v,
    int* __restrict__ gcur, int2* __restrict__ pairs, int E, int nbk)
{
    __shared__ int cnt[1024], base[1024];
    const int tid = threadIdx.x;
    const int tot = 2 * E;
    const int c0 = blockIdx.x * CH;
    const int nbk2 = 2 * nbk;
    for (int i = tid; i < nbk2; i += 256) cnt[i] = 0;
    __syncthreads();
    for (int i = 0; i < CH; i += 256) {
        int e = c0 + i + tid;
        if (e < tot) {
            int sc = e >= E;
            int vv = v[e];
            atomicAdd(&cnt[sc * nbk + (vv >> BKSH)], 1);
        }
    }
    __syncthreads();
    for (int i = tid; i < nbk2; i += 256) {
        int c = cnt[i];
        base[i] = c ? atomicAdd(&gcur[i], c) : 0;
        cnt[i] = 0;
    }
    __syncthreads();
    for (int i = 0; i < CH; i += 256) {
        int e = c0 + i + tid;
        if (e < tot) {
            int sc = e >= E;
            int uu = u[e], vv = v[e];
            int bk = sc * nbk + (vv >> BKSH);
            int off = atomicAdd(&cnt[bk], 1);
            pairs[(size_t)base[bk] + off] = make_int2(uu, vv);
        }
    }
}

// pass 2: per-bucket scatter into final CSR order (writes stay in ~10KB region)
__global__ __launch_bounds__(256) void bucket_fill(
    const int2* __restrict__ pairs, const int* __restrict__ rp,
    int* __restrict__ su, int E, int N, int nbk)
{
    __shared__ int curs[256];
    const int bk = blockIdx.x;
    const int sc = bk >= nbk;
    const int b = bk - sc * nbk;
    const int nb0 = b << BKSH;
    const int nb1 = min(nb0 + (1 << BKSH), N);
    const int nn = nb1 - nb0;
    const int* rps = rp + (size_t)sc * (N + 1);
    const int tid = threadIdx.x;
    const int rstart = rps[nb0], rend = rps[nb1];
    if (tid < nn) curs[tid] = rps[nb0 + tid];
    __syncthreads();
    int* sus = su + (size_t)sc * E;
    for (int idx = rstart + tid; idx < rend; idx += 256) {
        int2 pr = pairs[(size_t)sc * E + idx];
        int pos = atomicAdd(&curs[pr.y - nb0], 1);
        sus[pos] = pr.x;
    }
}

// agg[n][:] = max(0, max_{j in seg n} h1[su[j]][:])  -- bf16 bitwise u16 max
// 8-deep independent unroll: 8 gather rows in flight per wave
__global__ __launch_bounds__(256) void seg_max_bf(
    const int* __restrict__ rp, const int* __restrict__ su,
    const unsigned* __restrict__ h1, unsigned* __restrict__ agg, int N)
{
    int node = blockIdx.x * 4 + (threadIdx.x >> 6);
    int c = threadIdx.x & 63;
    if (node >= N) return;
    int s0 = rp[node], e0 = rp[node + 1];
    unsigned lo[8] = {0,0,0,0,0,0,0,0}, hi[8] = {0,0,0,0,0,0,0,0};
    int j = s0;
    for (; j + 7 < e0; j += 8) {
        unsigned x[8];
        #pragma unroll
        for (int q = 0; q < 8; ++q) x[q] = h1[(size_t)su[j + q] * 64 + c];
        #pragma unroll
        for (int q = 0; q < 8; ++q) {
            lo[q] = max(lo[q], x[q] & 0xffffu);
            hi[q] = max(hi[q], x[q] >> 16);
        }
    }
    for (; j < e0; ++j) {
        unsigned x0 = h1[(size_t)su[j] * 64 + c];
        lo[0] = max(lo[0], x0 & 0xffffu); hi[0] = max(hi[0], x0 >> 16);
    }
    #pragma unroll
    for (int q = 4; q > 0; q >>= 1)
        #pragma unroll
        for (int r = 0; r < q; ++r) {
            lo[r] = max(lo[r], lo[r + q]);
            hi[r] = max(hi[r], hi[r + q]);
        }
    agg[(size_t)node * 64 + c] = lo[0] | (hi[0] << 16);
}

// ---------------------------------------------------------------------------
extern "C" void kernel_launch(void* const* d_in, const int* in_sizes, int n_in,
                              void* d_out, int out_size, void* d_ws, size_t ws_size,
                              hipStream_t stream)
{
    const float* feats = (const float*)d_in[0];
    const int*   u     = (const int*)d_in[1];
    const int*   v     = (const int*)d_in[2];
    const float* in_w1 = (const float*)d_in[3];
    const float* in_g1 = (const float*)d_in[4];
    const float* in_b1 = (const float*)d_in[5];
    const float* in_w2 = (const float*)d_in[6];
    const float* in_g2 = (const float*)d_in[7];
    const float* in_b2 = (const float*)d_in[8];
    const float* in_wt = (const float*)d_in[9];
    const float* in_gt = (const float*)d_in[10];
    const float* in_bt = (const float*)d_in[11];
    const float* fc1_w = (const float*)d_in[12];
    const float* fc1_g = (const float*)d_in[13];
    const float* fc1_b = (const float*)d_in[14];
    const float* fc2_w = (const float*)d_in[15];
    const float* fc2_g = (const float*)d_in[16];
    const float* fc2_b = (const float*)d_in[17];
    const float* lin_w = (const float*)d_in[18];
    const float* lin_g = (const float*)d_in[19];
    const float* lin_b = (const float*)d_in[20];

    const int N = in_sizes[0] / 22;
    const int E = in_sizes[1] / 2;
    const size_t nmp = (size_t)(N + 64) * NMAP;

    unsigned short* fbf   = (unsigned short*)d_ws;     // running feat
    unsigned short* h1bf  = fbf + nmp;
    unsigned short* aggbf = h1bf + nmp;
    unsigned short* x32   = aggbf + nmp;               // padded input feats
    unsigned short* wts   = x32 + (size_t)(N + 64) * 32;
    unsigned short* wend  = wts + 286720;

    int* rp   = (int*)wend;          // 2*(N+1)
    int* su   = rp + 2 * (N + 1);    // 2*E
    int* part = su + 2 * (size_t)E;  // scan partials (<=128)
    int* gcur = part + 256;          // 2*nbk (<=1024)
    int2* pairs = (int2*)aggbf;      // 16 MB; aggbf free until first seg_max

    const int nbk = (N + (1 << BKSH) - 1) >> BKSH;     // buckets per scale

    // ---- one-time converts ----
    cvt_feats_kernel<<<((N + 64) * 32 + 255) / 256, 256, 0, stream>>>(feats, x32, N);
    cvt_all_w<<<(286720 + 255) / 256, 256, 0, stream>>>(
        in_w1, in_wt, in_w2, fc1_w, fc2_w, lin_w, wts);

    // ---- one-time CSR build ----
    {
        const int n1 = N + 1;
        const int NB = (n1 + SCHUNK - 1) / SCHUNK;
        hipMemsetAsync(rp, 0, 2 * (size_t)n1 * sizeof(int), stream);
        hist2_kernel<<<(2 * E + 255) / 256, 256, 0, stream>>>(v, rp, E, N);
        scan1_kernel<<<2 * NB, 256, 0, stream>>>(rp, part, n1, NB);
        scan2_kernel<<<2, 256, 0, stream>>>(part, NB);
        scan3_kernel<<<2 * (NB - 1), 256, 0, stream>>>(rp, part, n1, NB);
        init_gcur<<<(2 * nbk + 255) / 256, 256, 0, stream>>>(rp, gcur, E, N, nbk);
        bucket_scatter<<<(2 * E + CH - 1) / CH, 256, 0, stream>>>(
            u, v, gcur, pairs, E, nbk);
        bucket_fill<<<2 * nbk, 256, 0, stream>>>(pairs, rp, su, E, N, nbk);
    }

    const int GB = (N + 31) / 32;
    const int GS = (N + 3) / 4;

    // ---- input stage + fc1[0] ----
    input_fused<<<GB, 256, 0, stream>>>(x32, wts,
        in_g1, in_b1, in_gt, in_bt, in_g2, in_b2,
        fc1_g, fc1_b, fbf, h1bf, N);

    // ---- agg blocks ----
    for (int k = 0; k < 4; ++k) {
        int is = k & 1;
        int has_next = (k < 3);
        seg_max_bf<<<GS, 256, 0, stream>>>(rp + (size_t)is * (N + 1),
            su + (size_t)is * E, (const unsigned*)h1bf, (unsigned*)aggbf, N);
        block_fused<<<GB, 256, 0, stream>>>(fbf, aggbf, wts, k,
            fc2_g + k * 128, fc2_b + k * 128,
            lin_g + k * 128, lin_b + k * 128,
            has_next ? fc1_g + (k + 1) * 128 : nullptr,
            has_next ? fc1_b + (k + 1) * 128 : nullptr,
            h1bf, (k == 3) ? (float*)d_out : nullptr, N, has_next);
    }
}